// Round 1
// baseline (2325.780 us; speedup 1.0000x reference)
//
#include <hip/hip_runtime.h>
#include <math.h>

#define N_NODES 100000
#define N_EDGES 1600000

// ---------------- degree ----------------
__global__ void deg_kernel(const int* __restrict__ dst, float* __restrict__ deg, int nE) {
    int e = blockIdx.x * blockDim.x + threadIdx.x;
    if (e < nE) atomicAdd(&deg[dst[e]], 1.0f);
}

__global__ void invdeg_kernel(float* __restrict__ deg, int n) {
    int i = blockIdx.x * blockDim.x + threadIdx.x;
    if (i < n) deg[i] = 1.0f / fmaxf(deg[i], 1.0f);
}

// ---------------- scatter: msg[dst] += x[src], thread = (edge, feat) ----------------
__global__ void scatter_kernel(const int* __restrict__ src, const int* __restrict__ dst,
                               const float* __restrict__ x, float* __restrict__ msg, int nE) {
    int gid = blockIdx.x * blockDim.x + threadIdx.x;
    int e = gid >> 6;
    int d = gid & 63;
    if (e < nE) {
        int s = src[e];
        int t = dst[e];
        atomicAdd(&msg[(size_t)t * 64 + d], x[(size_t)s * 64 + d]);
    }
}

// ---------------- transform: out = relu(mean@Wl.T + b + x@Wr.T), DOUT outputs ----------------
template <int DOUT>
__global__ void transform_kernel(const float* __restrict__ xin, const float* __restrict__ msg,
                                 const float* __restrict__ invdeg,
                                 const float* __restrict__ Wl, const float* __restrict__ b,
                                 const float* __restrict__ Wr,
                                 float* __restrict__ out, int n) {
    __shared__ float sWl[DOUT * 64];
    __shared__ float sWr[DOUT * 64];
    __shared__ float sb[DOUT];
    for (int i = threadIdx.x; i < DOUT * 64; i += blockDim.x) {
        sWl[i] = Wl[i];
        sWr[i] = Wr[i];
    }
    for (int i = threadIdx.x; i < DOUT; i += blockDim.x) sb[i] = b[i];
    __syncthreads();

    int node = blockIdx.x * blockDim.x + threadIdx.x;
    if (node >= n) return;

    float id = invdeg[node];
    const float4* xp = (const float4*)(xin + (size_t)node * 64);
    const float4* mp = (const float4*)(msg + (size_t)node * 64);
    float xr[64], mr[64];
#pragma unroll
    for (int i = 0; i < 16; i++) {
        float4 a = xp[i];
        float4 c = mp[i];
        xr[4 * i + 0] = a.x; xr[4 * i + 1] = a.y; xr[4 * i + 2] = a.z; xr[4 * i + 3] = a.w;
        mr[4 * i + 0] = c.x * id; mr[4 * i + 1] = c.y * id; mr[4 * i + 2] = c.z * id; mr[4 * i + 3] = c.w * id;
    }

#pragma unroll 1
    for (int j = 0; j < DOUT; j++) {
        float acc = sb[j];
#pragma unroll
        for (int k = 0; k < 64; k++) {
            acc = fmaf(mr[k], sWl[j * 64 + k], acc);
            acc = fmaf(xr[k], sWr[j * 64 + k], acc);
        }
        out[(size_t)node * DOUT + j] = fmaxf(acc, 0.0f);
    }
}

// ---------------- layer 3 + regression head fused ----------------
__global__ void transform3_kernel(const float* __restrict__ xin, const float* __restrict__ msg,
                                  const float* __restrict__ invdeg,
                                  const float* __restrict__ Wl, const float* __restrict__ b,
                                  const float* __restrict__ Wr,
                                  const float* __restrict__ Wreg, const float* __restrict__ breg,
                                  float* __restrict__ out, int n) {
    __shared__ float sWl[32 * 64];
    __shared__ float sWr[32 * 64];
    __shared__ float sb[32];
    __shared__ float sWreg[32];
    for (int i = threadIdx.x; i < 32 * 64; i += blockDim.x) {
        sWl[i] = Wl[i];
        sWr[i] = Wr[i];
    }
    if (threadIdx.x < 32) {
        sb[threadIdx.x] = b[threadIdx.x];
        sWreg[threadIdx.x] = Wreg[threadIdx.x];
    }
    __syncthreads();

    int node = blockIdx.x * blockDim.x + threadIdx.x;
    if (node >= n) return;

    float id = invdeg[node];
    const float4* xp = (const float4*)(xin + (size_t)node * 64);
    const float4* mp = (const float4*)(msg + (size_t)node * 64);
    float xr[64], mr[64];
#pragma unroll
    for (int i = 0; i < 16; i++) {
        float4 a = xp[i];
        float4 c = mp[i];
        xr[4 * i + 0] = a.x; xr[4 * i + 1] = a.y; xr[4 * i + 2] = a.z; xr[4 * i + 3] = a.w;
        mr[4 * i + 0] = c.x * id; mr[4 * i + 1] = c.y * id; mr[4 * i + 2] = c.z * id; mr[4 * i + 3] = c.w * id;
    }

    float result = breg[0];
#pragma unroll 1
    for (int j = 0; j < 32; j++) {
        float acc = sb[j];
#pragma unroll
        for (int k = 0; k < 64; k++) {
            acc = fmaf(mr[k], sWl[j * 64 + k], acc);
            acc = fmaf(xr[k], sWr[j * 64 + k], acc);
        }
        result = fmaf(fmaxf(acc, 0.0f), sWreg[j], result);
    }
    out[node] = result;
}

extern "C" void kernel_launch(void* const* d_in, const int* in_sizes, int n_in,
                              void* d_out, int out_size, void* d_ws, size_t ws_size,
                              hipStream_t stream) {
    const float* x    = (const float*)d_in[0];
    const int*   ei   = (const int*)d_in[1];
    const float* W1l  = (const float*)d_in[2];
    const float* b1   = (const float*)d_in[3];
    const float* W1r  = (const float*)d_in[4];
    const float* W2l  = (const float*)d_in[5];
    const float* b2   = (const float*)d_in[6];
    const float* W2r  = (const float*)d_in[7];
    const float* W3l  = (const float*)d_in[8];
    const float* b3   = (const float*)d_in[9];
    const float* W3r  = (const float*)d_in[10];
    const float* Wreg = (const float*)d_in[11];
    const float* breg = (const float*)d_in[12];

    const int* src = ei;
    const int* dst = ei + N_EDGES;

    float* ws   = (float*)d_ws;
    float* deg  = ws;                       // N floats (becomes inv_deg)
    float* msg  = deg + N_NODES;            // N*64 floats
    float* h1   = msg + (size_t)N_NODES * 64;  // N*64
    float* h2   = h1 + (size_t)N_NODES * 64;   // N*64
    float* out  = (float*)d_out;

    const int TB = 256;
    int edgeBlocks   = (N_EDGES + TB - 1) / TB;
    int scatBlocks   = (int)(((size_t)N_EDGES * 64 + TB - 1) / TB);
    int nodeBlocks   = (N_NODES + TB - 1) / TB;

    // degree (recomputed each call; deterministic)
    hipMemsetAsync(deg, 0, N_NODES * sizeof(float), stream);
    deg_kernel<<<edgeBlocks, TB, 0, stream>>>(dst, deg, N_EDGES);
    invdeg_kernel<<<nodeBlocks, TB, 0, stream>>>(deg, N_NODES);

    // layer 1
    hipMemsetAsync(msg, 0, (size_t)N_NODES * 64 * sizeof(float), stream);
    scatter_kernel<<<scatBlocks, TB, 0, stream>>>(src, dst, x, msg, N_EDGES);
    transform_kernel<64><<<nodeBlocks, TB, 0, stream>>>(x, msg, deg, W1l, b1, W1r, h1, N_NODES);

    // layer 2
    hipMemsetAsync(msg, 0, (size_t)N_NODES * 64 * sizeof(float), stream);
    scatter_kernel<<<scatBlocks, TB, 0, stream>>>(src, dst, h1, msg, N_EDGES);
    transform_kernel<64><<<nodeBlocks, TB, 0, stream>>>(h1, msg, deg, W2l, b2, W2r, h2, N_NODES);

    // layer 3 + head
    hipMemsetAsync(msg, 0, (size_t)N_NODES * 64 * sizeof(float), stream);
    scatter_kernel<<<scatBlocks, TB, 0, stream>>>(src, dst, h2, msg, N_EDGES);
    transform3_kernel<<<nodeBlocks, TB, 0, stream>>>(h2, msg, deg, W3l, b3, W3r, Wreg, breg, out, N_NODES);
}

// Round 2
// 657.462 us; speedup vs baseline: 3.5375x; 3.5375x over previous
//
#include <hip/hip_runtime.h>
#include <math.h>

#define N_NODES 100000
#define N_EDGES 1600000

// ---------------- CSR build ----------------
__global__ void hist_kernel(const int* __restrict__ dst, int* __restrict__ cnt, int nE) {
    int e = blockIdx.x * blockDim.x + threadIdx.x;
    if (e < nE) atomicAdd(&cnt[dst[e]], 1);
}

// inclusive scan of 256-element chunks
__global__ void scan_chunk(const int* __restrict__ in, int* __restrict__ partial,
                           int* __restrict__ sums, int n) {
    __shared__ int s[256];
    int gid = blockIdx.x * 256 + threadIdx.x;
    int v = (gid < n) ? in[gid] : 0;
    s[threadIdx.x] = v;
    __syncthreads();
    for (int off = 1; off < 256; off <<= 1) {
        int t = (threadIdx.x >= (unsigned)off) ? s[threadIdx.x - off] : 0;
        __syncthreads();
        s[threadIdx.x] += t;
        __syncthreads();
    }
    if (gid < n) partial[gid] = s[threadIdx.x];
    if (threadIdx.x == 255) sums[blockIdx.x] = s[255];
}

// single-block inclusive scan of the chunk sums (nsums <= 512)
__global__ void scan_sums(int* __restrict__ sums, int nsums) {
    __shared__ int s[512];
    int tid = threadIdx.x;
    int v = (tid < nsums) ? sums[tid] : 0;
    s[tid] = v;
    __syncthreads();
    for (int off = 1; off < 512; off <<= 1) {
        int t = (tid >= off) ? s[tid - off] : 0;
        __syncthreads();
        s[tid] += t;
        __syncthreads();
    }
    if (tid < nsums) sums[tid] = s[tid];
}

__global__ void finalize_rowptr(const int* __restrict__ partial, const int* __restrict__ sums,
                                int* __restrict__ rowptr, int n) {
    int gid = blockIdx.x * 256 + threadIdx.x;
    if (gid < n) {
        int base = (blockIdx.x > 0) ? sums[blockIdx.x - 1] : 0;
        rowptr[gid + 1] = partial[gid] + base;
        if (gid == 0) rowptr[0] = 0;
    }
}

__global__ void invdeg_rowptr(const int* __restrict__ rowptr, float* __restrict__ invdeg, int n) {
    int gid = blockIdx.x * blockDim.x + threadIdx.x;
    if (gid < n) {
        int d = rowptr[gid + 1] - rowptr[gid];
        invdeg[gid] = 1.0f / fmaxf((float)d, 1.0f);
    }
}

__global__ void fill_kernel(const int* __restrict__ src, const int* __restrict__ dst,
                            const int* __restrict__ rowptr, int* __restrict__ fill,
                            int* __restrict__ col, int nE) {
    int e = blockIdx.x * blockDim.x + threadIdx.x;
    if (e < nE) {
        int d = dst[e];
        int pos = rowptr[d] + atomicAdd(&fill[d], 1);
        col[pos] = src[e];
    }
}

// ---------------- gather mean: wave per node, lane = feature ----------------
__global__ void gather_mean(const float* __restrict__ x, const int* __restrict__ rowptr,
                            const int* __restrict__ col, const float* __restrict__ invdeg,
                            float* __restrict__ mean, int n) {
    int wave = threadIdx.x >> 6;
    int lane = threadIdx.x & 63;
    int node = blockIdx.x * 4 + wave;
    if (node >= n) return;
    int beg = rowptr[node];
    int end = rowptr[node + 1];
    float acc = 0.0f;
    for (int i = beg; i < end; i += 64) {
        int idx = i + lane;
        int ci = (idx < end) ? col[idx] : 0;
        int cnt = min(64, end - i);
        for (int j = 0; j < cnt; ++j) {
            int s = __shfl(ci, j, 64);
            acc += x[(size_t)s * 64 + lane];
        }
    }
    mean[(size_t)node * 64 + lane] = acc * invdeg[node];
}

// ---------------- transform: out = relu(mean@Wl.T + b + x@Wr.T) ----------------
// acc[DOUT] in registers (statically indexed), x/mean streamed in float4 chunks.
template <int DOUT>
__global__ void transform_kernel(const float* __restrict__ xin, const float* __restrict__ mean,
                                 const float* __restrict__ Wl, const float* __restrict__ b,
                                 const float* __restrict__ Wr,
                                 float* __restrict__ out, int n) {
    __shared__ __align__(16) float sWl[DOUT * 64];
    __shared__ __align__(16) float sWr[DOUT * 64];
    __shared__ float sb[DOUT];
    for (int i = threadIdx.x; i < DOUT * 64; i += blockDim.x) {
        sWl[i] = Wl[i];
        sWr[i] = Wr[i];
    }
    for (int i = threadIdx.x; i < DOUT; i += blockDim.x) sb[i] = b[i];
    __syncthreads();

    int node = blockIdx.x * blockDim.x + threadIdx.x;
    if (node >= n) return;

    const float4* xp = (const float4*)(xin + (size_t)node * 64);
    const float4* mp = (const float4*)(mean + (size_t)node * 64);

    float acc[DOUT];
#pragma unroll
    for (int j = 0; j < DOUT; ++j) acc[j] = sb[j];

#pragma unroll 1
    for (int kk = 0; kk < 16; ++kk) {
        float4 xv = xp[kk];
        float4 mv = mp[kk];
#pragma unroll
        for (int j = 0; j < DOUT; ++j) {
            const float4 wl = *(const float4*)&sWl[j * 64 + kk * 4];
            const float4 wr = *(const float4*)&sWr[j * 64 + kk * 4];
            float a = acc[j];
            a = fmaf(mv.x, wl.x, a); a = fmaf(mv.y, wl.y, a);
            a = fmaf(mv.z, wl.z, a); a = fmaf(mv.w, wl.w, a);
            a = fmaf(xv.x, wr.x, a); a = fmaf(xv.y, wr.y, a);
            a = fmaf(xv.z, wr.z, a); a = fmaf(xv.w, wr.w, a);
            acc[j] = a;
        }
    }

    float4* op = (float4*)(out + (size_t)node * DOUT);
#pragma unroll
    for (int q = 0; q < DOUT / 4; ++q) {
        float4 o;
        o.x = fmaxf(acc[4 * q + 0], 0.0f);
        o.y = fmaxf(acc[4 * q + 1], 0.0f);
        o.z = fmaxf(acc[4 * q + 2], 0.0f);
        o.w = fmaxf(acc[4 * q + 3], 0.0f);
        op[q] = o;
    }
}

// ---------------- layer 3 + regression head fused (DOUT=32) ----------------
__global__ void transform3_kernel(const float* __restrict__ xin, const float* __restrict__ mean,
                                  const float* __restrict__ Wl, const float* __restrict__ b,
                                  const float* __restrict__ Wr,
                                  const float* __restrict__ Wreg, const float* __restrict__ breg,
                                  float* __restrict__ out, int n) {
    __shared__ __align__(16) float sWl[32 * 64];
    __shared__ __align__(16) float sWr[32 * 64];
    __shared__ float sb[32];
    __shared__ float sWreg[32];
    for (int i = threadIdx.x; i < 32 * 64; i += blockDim.x) {
        sWl[i] = Wl[i];
        sWr[i] = Wr[i];
    }
    if (threadIdx.x < 32) {
        sb[threadIdx.x] = b[threadIdx.x];
        sWreg[threadIdx.x] = Wreg[threadIdx.x];
    }
    __syncthreads();

    int node = blockIdx.x * blockDim.x + threadIdx.x;
    if (node >= n) return;

    const float4* xp = (const float4*)(xin + (size_t)node * 64);
    const float4* mp = (const float4*)(mean + (size_t)node * 64);

    float acc[32];
#pragma unroll
    for (int j = 0; j < 32; ++j) acc[j] = sb[j];

#pragma unroll 1
    for (int kk = 0; kk < 16; ++kk) {
        float4 xv = xp[kk];
        float4 mv = mp[kk];
#pragma unroll
        for (int j = 0; j < 32; ++j) {
            const float4 wl = *(const float4*)&sWl[j * 64 + kk * 4];
            const float4 wr = *(const float4*)&sWr[j * 64 + kk * 4];
            float a = acc[j];
            a = fmaf(mv.x, wl.x, a); a = fmaf(mv.y, wl.y, a);
            a = fmaf(mv.z, wl.z, a); a = fmaf(mv.w, wl.w, a);
            a = fmaf(xv.x, wr.x, a); a = fmaf(xv.y, wr.y, a);
            a = fmaf(xv.z, wr.z, a); a = fmaf(xv.w, wr.w, a);
            acc[j] = a;
        }
    }

    float result = breg[0];
#pragma unroll
    for (int j = 0; j < 32; ++j) result = fmaf(fmaxf(acc[j], 0.0f), sWreg[j], result);
    out[node] = result;
}

extern "C" void kernel_launch(void* const* d_in, const int* in_sizes, int n_in,
                              void* d_out, int out_size, void* d_ws, size_t ws_size,
                              hipStream_t stream) {
    const float* x    = (const float*)d_in[0];
    const int*   ei   = (const int*)d_in[1];
    const float* W1l  = (const float*)d_in[2];
    const float* b1   = (const float*)d_in[3];
    const float* W1r  = (const float*)d_in[4];
    const float* W2l  = (const float*)d_in[5];
    const float* b2   = (const float*)d_in[6];
    const float* W2r  = (const float*)d_in[7];
    const float* W3l  = (const float*)d_in[8];
    const float* b3   = (const float*)d_in[9];
    const float* W3r  = (const float*)d_in[10];
    const float* Wreg = (const float*)d_in[11];
    const float* breg = (const float*)d_in[12];

    const int* src = ei;
    const int* dst = ei + N_EDGES;

    // workspace layout (bump allocator, 256B aligned)
    char* p = (char*)d_ws;
    auto alloc = [&](size_t bytes) {
        char* r = p;
        p += (bytes + 255) & ~(size_t)255;
        return r;
    };
    int*   degcnt = (int*)alloc(N_NODES * sizeof(int));      // reused as fill counter
    int*   rowptr = (int*)alloc((N_NODES + 1) * sizeof(int));
    int*   partial= (int*)alloc(N_NODES * sizeof(int));
    int*   sums   = (int*)alloc(512 * sizeof(int));
    int*   col    = (int*)alloc((size_t)N_EDGES * sizeof(int));
    float* invdeg = (float*)alloc(N_NODES * sizeof(float));
    float* mean   = (float*)alloc((size_t)N_NODES * 64 * sizeof(float));
    float* h      = (float*)alloc((size_t)N_NODES * 64 * sizeof(float));
    float* out    = (float*)d_out;

    const int TB = 256;
    int edgeBlocks = (N_EDGES + TB - 1) / TB;
    int nodeBlocks = (N_NODES + TB - 1) / TB;   // 391
    int gatherBlocks = (N_NODES + 3) / 4;       // 4 waves/block, wave per node

    // ---- CSR build (every call; deterministic topology) ----
    hipMemsetAsync(degcnt, 0, N_NODES * sizeof(int), stream);
    hist_kernel<<<edgeBlocks, TB, 0, stream>>>(dst, degcnt, N_EDGES);
    scan_chunk<<<nodeBlocks, 256, 0, stream>>>(degcnt, partial, sums, N_NODES);
    scan_sums<<<1, 512, 0, stream>>>(sums, nodeBlocks);
    finalize_rowptr<<<nodeBlocks, 256, 0, stream>>>(partial, sums, rowptr, N_NODES);
    invdeg_rowptr<<<nodeBlocks, TB, 0, stream>>>(rowptr, invdeg, N_NODES);
    hipMemsetAsync(degcnt, 0, N_NODES * sizeof(int), stream);
    fill_kernel<<<edgeBlocks, TB, 0, stream>>>(src, dst, rowptr, degcnt, col, N_EDGES);

    // ---- layer 1 ----
    gather_mean<<<gatherBlocks, 256, 0, stream>>>(x, rowptr, col, invdeg, mean, N_NODES);
    transform_kernel<64><<<nodeBlocks, TB, 0, stream>>>(x, mean, W1l, b1, W1r, h, N_NODES);

    // ---- layer 2 (in-place on h) ----
    gather_mean<<<gatherBlocks, 256, 0, stream>>>(h, rowptr, col, invdeg, mean, N_NODES);
    transform_kernel<64><<<nodeBlocks, TB, 0, stream>>>(h, mean, W2l, b2, W2r, h, N_NODES);

    // ---- layer 3 + head ----
    gather_mean<<<gatherBlocks, 256, 0, stream>>>(h, rowptr, col, invdeg, mean, N_NODES);
    transform3_kernel<<<nodeBlocks, TB, 0, stream>>>(h, mean, W3l, b3, W3r, Wreg, breg, out, N_NODES);
}

// Round 3
// 504.824 us; speedup vs baseline: 4.6071x; 1.3024x over previous
//
#include <hip/hip_runtime.h>
#include <math.h>

#define N_NODES 100000
#define N_EDGES 1600000

typedef unsigned int uint;
typedef unsigned short ushort_t;

__device__ inline ushort f2bf(float f) {
    uint u = __float_as_uint(f);
    uint r = (u + 0x7fffu + ((u >> 16) & 1u)) >> 16;
    return (ushort)r;
}
__device__ inline uint pack2bf(float lo, float hi) {
    return (uint)f2bf(lo) | ((uint)f2bf(hi) << 16);
}

// ---------------- cast x -> bf16 ----------------
__global__ void cast_bf16(const float* __restrict__ in, ushort* __restrict__ out, int n4) {
    int i = blockIdx.x * blockDim.x + threadIdx.x;
    if (i < n4) {
        float4 v = ((const float4*)in)[i];
        uint2 o;
        o.x = pack2bf(v.x, v.y);
        o.y = pack2bf(v.z, v.w);
        ((uint2*)out)[i] = o;
    }
}

// ---------------- CSR build ----------------
__global__ void hist_kernel(const int* __restrict__ dst, int* __restrict__ cnt, int nE) {
    int e = blockIdx.x * blockDim.x + threadIdx.x;
    if (e < nE) atomicAdd(&cnt[dst[e]], 1);
}

__global__ void scan_chunk(const int* __restrict__ in, int* __restrict__ partial,
                           int* __restrict__ sums, int n) {
    __shared__ int s[256];
    int gid = blockIdx.x * 256 + threadIdx.x;
    int v = (gid < n) ? in[gid] : 0;
    s[threadIdx.x] = v;
    __syncthreads();
    for (int off = 1; off < 256; off <<= 1) {
        int t = (threadIdx.x >= (unsigned)off) ? s[threadIdx.x - off] : 0;
        __syncthreads();
        s[threadIdx.x] += t;
        __syncthreads();
    }
    if (gid < n) partial[gid] = s[threadIdx.x];
    if (threadIdx.x == 255) sums[blockIdx.x] = s[255];
}

__global__ void scan_sums(int* __restrict__ sums, int nsums) {
    __shared__ int s[512];
    int tid = threadIdx.x;
    int v = (tid < nsums) ? sums[tid] : 0;
    s[tid] = v;
    __syncthreads();
    for (int off = 1; off < 512; off <<= 1) {
        int t = (tid >= off) ? s[tid - off] : 0;
        __syncthreads();
        s[tid] += t;
        __syncthreads();
    }
    if (tid < nsums) sums[tid] = s[tid];
}

__global__ void finalize_rowptr(const int* __restrict__ partial, const int* __restrict__ sums,
                                int* __restrict__ rowptr, int n) {
    int gid = blockIdx.x * 256 + threadIdx.x;
    if (gid < n) {
        int base = (blockIdx.x > 0) ? sums[blockIdx.x - 1] : 0;
        rowptr[gid + 1] = partial[gid] + base;
        if (gid == 0) rowptr[0] = 0;
    }
}

__global__ void invdeg_rowptr(const int* __restrict__ rowptr, float* __restrict__ invdeg, int n) {
    int gid = blockIdx.x * blockDim.x + threadIdx.x;
    if (gid < n) {
        int d = rowptr[gid + 1] - rowptr[gid];
        invdeg[gid] = 1.0f / fmaxf((float)d, 1.0f);
    }
}

__global__ void fill_kernel(const int* __restrict__ src, const int* __restrict__ dst,
                            const int* __restrict__ rowptr, int* __restrict__ fill,
                            int* __restrict__ col, int nE) {
    int e = blockIdx.x * blockDim.x + threadIdx.x;
    if (e < nE) {
        int d = dst[e];
        int pos = rowptr[d] + atomicAdd(&fill[d], 1);
        col[pos] = src[e];
    }
}

// ---------------- gather mean: wave per node, 4 edges per VMEM instr ----------------
// 16-lane group g handles edge (t*4+g); lane (l&15) loads 4 bf16 features as dwordx2.
__global__ void gather_mean(const ushort* __restrict__ xb, const int* __restrict__ rowptr,
                            const int* __restrict__ col, const float* __restrict__ invdeg,
                            ushort* __restrict__ meanb, int n) {
    int wave = threadIdx.x >> 6;
    int lane = threadIdx.x & 63;
    int node = blockIdx.x * 4 + wave;
    if (node >= n) return;
    int beg = rowptr[node];
    int end = rowptr[node + 1];
    int grp = lane >> 4;
    int fb = (lane & 15) * 4;
    float a0 = 0.0f, a1 = 0.0f, a2 = 0.0f, a3 = 0.0f;
    for (int i = beg; i < end; i += 64) {
        int idx = i + lane;
        int ci = (idx < end) ? col[idx] : 0;
        int cnt = min(64, end - i);
        int nq = (cnt + 3) >> 2;
#pragma unroll 4
        for (int t = 0; t < nq; ++t) {
            int e = t * 4 + grp;
            int s = __shfl(ci, e, 64);
            if (e < cnt) {
                uint2 w = *(const uint2*)(xb + (size_t)s * 64 + fb);
                a0 += __uint_as_float(w.x << 16);
                a1 += __uint_as_float(w.x & 0xffff0000u);
                a2 += __uint_as_float(w.y << 16);
                a3 += __uint_as_float(w.y & 0xffff0000u);
            }
        }
    }
    // combine the 4 groups (butterfly over lane bits 4,5)
    a0 += __shfl_xor(a0, 16, 64); a0 += __shfl_xor(a0, 32, 64);
    a1 += __shfl_xor(a1, 16, 64); a1 += __shfl_xor(a1, 32, 64);
    a2 += __shfl_xor(a2, 16, 64); a2 += __shfl_xor(a2, 32, 64);
    a3 += __shfl_xor(a3, 16, 64); a3 += __shfl_xor(a3, 32, 64);
    if (grp == 0) {
        float id = invdeg[node];
        uint2 o;
        o.x = pack2bf(a0 * id, a1 * id);
        o.y = pack2bf(a2 * id, a3 * id);
        *(uint2*)(meanb + (size_t)node * 64 + fb) = o;
    }
}

// ---------------- transform: out = relu(mean@Wl.T + b + x@Wr.T) ----------------
// root path fp32, mean path bf16; writes fp32 + bf16 copies of h.
template <int DOUT>
__global__ void transform_kernel(const float* __restrict__ xroot, const ushort* __restrict__ meanb,
                                 const float* __restrict__ Wl, const float* __restrict__ b,
                                 const float* __restrict__ Wr,
                                 float* __restrict__ outf, ushort* __restrict__ outb, int n) {
    __shared__ __align__(16) float sWl[DOUT * 64];
    __shared__ __align__(16) float sWr[DOUT * 64];
    __shared__ float sb[DOUT];
    for (int i = threadIdx.x; i < DOUT * 64; i += blockDim.x) {
        sWl[i] = Wl[i];
        sWr[i] = Wr[i];
    }
    for (int i = threadIdx.x; i < DOUT; i += blockDim.x) sb[i] = b[i];
    __syncthreads();

    int node = blockIdx.x * blockDim.x + threadIdx.x;
    if (node >= n) return;

    const float4* xp = (const float4*)(xroot + (size_t)node * 64);
    const uint2* mp = (const uint2*)(meanb + (size_t)node * 64);

    float acc[DOUT];
#pragma unroll
    for (int j = 0; j < DOUT; ++j) acc[j] = sb[j];

#pragma unroll 1
    for (int kk = 0; kk < 16; ++kk) {
        float4 xv = xp[kk];
        uint2 mw = mp[kk];
        float4 mv;
        mv.x = __uint_as_float(mw.x << 16);
        mv.y = __uint_as_float(mw.x & 0xffff0000u);
        mv.z = __uint_as_float(mw.y << 16);
        mv.w = __uint_as_float(mw.y & 0xffff0000u);
#pragma unroll
        for (int j = 0; j < DOUT; ++j) {
            const float4 wl = *(const float4*)&sWl[j * 64 + kk * 4];
            const float4 wr = *(const float4*)&sWr[j * 64 + kk * 4];
            float a = acc[j];
            a = fmaf(mv.x, wl.x, a); a = fmaf(mv.y, wl.y, a);
            a = fmaf(mv.z, wl.z, a); a = fmaf(mv.w, wl.w, a);
            a = fmaf(xv.x, wr.x, a); a = fmaf(xv.y, wr.y, a);
            a = fmaf(xv.z, wr.z, a); a = fmaf(xv.w, wr.w, a);
            acc[j] = a;
        }
    }

#pragma unroll
    for (int j = 0; j < DOUT; ++j) acc[j] = fmaxf(acc[j], 0.0f);

    float4* op = (float4*)(outf + (size_t)node * DOUT);
#pragma unroll
    for (int q = 0; q < DOUT / 4; ++q) {
        float4 o;
        o.x = acc[4 * q + 0]; o.y = acc[4 * q + 1];
        o.z = acc[4 * q + 2]; o.w = acc[4 * q + 3];
        op[q] = o;
    }
    uint4* obp = (uint4*)(outb + (size_t)node * DOUT);
#pragma unroll
    for (int q = 0; q < DOUT / 8; ++q) {
        uint4 o;
        o.x = pack2bf(acc[8 * q + 0], acc[8 * q + 1]);
        o.y = pack2bf(acc[8 * q + 2], acc[8 * q + 3]);
        o.z = pack2bf(acc[8 * q + 4], acc[8 * q + 5]);
        o.w = pack2bf(acc[8 * q + 6], acc[8 * q + 7]);
        obp[q] = o;
    }
}

// ---------------- layer 3 + regression head fused (DOUT=32) ----------------
__global__ void transform3_kernel(const float* __restrict__ xroot, const ushort* __restrict__ meanb,
                                  const float* __restrict__ Wl, const float* __restrict__ b,
                                  const float* __restrict__ Wr,
                                  const float* __restrict__ Wreg, const float* __restrict__ breg,
                                  float* __restrict__ out, int n) {
    __shared__ __align__(16) float sWl[32 * 64];
    __shared__ __align__(16) float sWr[32 * 64];
    __shared__ float sb[32];
    __shared__ float sWreg[32];
    for (int i = threadIdx.x; i < 32 * 64; i += blockDim.x) {
        sWl[i] = Wl[i];
        sWr[i] = Wr[i];
    }
    if (threadIdx.x < 32) {
        sb[threadIdx.x] = b[threadIdx.x];
        sWreg[threadIdx.x] = Wreg[threadIdx.x];
    }
    __syncthreads();

    int node = blockIdx.x * blockDim.x + threadIdx.x;
    if (node >= n) return;

    const float4* xp = (const float4*)(xroot + (size_t)node * 64);
    const uint2* mp = (const uint2*)(meanb + (size_t)node * 64);

    float acc[32];
#pragma unroll
    for (int j = 0; j < 32; ++j) acc[j] = sb[j];

#pragma unroll 1
    for (int kk = 0; kk < 16; ++kk) {
        float4 xv = xp[kk];
        uint2 mw = mp[kk];
        float4 mv;
        mv.x = __uint_as_float(mw.x << 16);
        mv.y = __uint_as_float(mw.x & 0xffff0000u);
        mv.z = __uint_as_float(mw.y << 16);
        mv.w = __uint_as_float(mw.y & 0xffff0000u);
#pragma unroll
        for (int j = 0; j < 32; ++j) {
            const float4 wl = *(const float4*)&sWl[j * 64 + kk * 4];
            const float4 wr = *(const float4*)&sWr[j * 64 + kk * 4];
            float a = acc[j];
            a = fmaf(mv.x, wl.x, a); a = fmaf(mv.y, wl.y, a);
            a = fmaf(mv.z, wl.z, a); a = fmaf(mv.w, wl.w, a);
            a = fmaf(xv.x, wr.x, a); a = fmaf(xv.y, wr.y, a);
            a = fmaf(xv.z, wr.z, a); a = fmaf(xv.w, wr.w, a);
            acc[j] = a;
        }
    }

    float result = breg[0];
#pragma unroll
    for (int j = 0; j < 32; ++j) result = fmaf(fmaxf(acc[j], 0.0f), sWreg[j], result);
    out[node] = result;
}

extern "C" void kernel_launch(void* const* d_in, const int* in_sizes, int n_in,
                              void* d_out, int out_size, void* d_ws, size_t ws_size,
                              hipStream_t stream) {
    const float* x    = (const float*)d_in[0];
    const int*   ei   = (const int*)d_in[1];
    const float* W1l  = (const float*)d_in[2];
    const float* b1   = (const float*)d_in[3];
    const float* W1r  = (const float*)d_in[4];
    const float* W2l  = (const float*)d_in[5];
    const float* b2   = (const float*)d_in[6];
    const float* W2r  = (const float*)d_in[7];
    const float* W3l  = (const float*)d_in[8];
    const float* b3   = (const float*)d_in[9];
    const float* W3r  = (const float*)d_in[10];
    const float* Wreg = (const float*)d_in[11];
    const float* breg = (const float*)d_in[12];

    const int* src = ei;
    const int* dst = ei + N_EDGES;

    char* p = (char*)d_ws;
    auto alloc = [&](size_t bytes) {
        char* r = p;
        p += (bytes + 255) & ~(size_t)255;
        return r;
    };
    int*    degcnt = (int*)alloc(N_NODES * sizeof(int));
    int*    rowptr = (int*)alloc((N_NODES + 1) * sizeof(int));
    int*    partial= (int*)alloc(N_NODES * sizeof(int));
    int*    sums   = (int*)alloc(512 * sizeof(int));
    int*    col    = (int*)alloc((size_t)N_EDGES * sizeof(int));
    float*  invdeg = (float*)alloc(N_NODES * sizeof(float));
    ushort* xb     = (ushort*)alloc((size_t)N_NODES * 64 * sizeof(ushort));
    ushort* meanb  = (ushort*)alloc((size_t)N_NODES * 64 * sizeof(ushort));
    ushort* hb     = (ushort*)alloc((size_t)N_NODES * 64 * sizeof(ushort));
    float*  hf     = (float*)alloc((size_t)N_NODES * 64 * sizeof(float));
    float*  out    = (float*)d_out;

    const int TB = 256;
    int edgeBlocks   = (N_EDGES + TB - 1) / TB;
    int nodeBlocks   = (N_NODES + TB - 1) / TB;
    int gatherBlocks = (N_NODES + 3) / 4;
    int castBlocks   = ((N_NODES * 64 / 4) + TB - 1) / TB;

    // ---- CSR build ----
    hipMemsetAsync(degcnt, 0, N_NODES * sizeof(int), stream);
    hist_kernel<<<edgeBlocks, TB, 0, stream>>>(dst, degcnt, N_EDGES);
    cast_bf16<<<castBlocks, TB, 0, stream>>>(x, xb, N_NODES * 64 / 4);
    scan_chunk<<<nodeBlocks, 256, 0, stream>>>(degcnt, partial, sums, N_NODES);
    scan_sums<<<1, 512, 0, stream>>>(sums, nodeBlocks);
    finalize_rowptr<<<nodeBlocks, 256, 0, stream>>>(partial, sums, rowptr, N_NODES);
    invdeg_rowptr<<<nodeBlocks, TB, 0, stream>>>(rowptr, invdeg, N_NODES);
    hipMemsetAsync(degcnt, 0, N_NODES * sizeof(int), stream);
    fill_kernel<<<edgeBlocks, TB, 0, stream>>>(src, dst, rowptr, degcnt, col, N_EDGES);

    // ---- layer 1 ----
    gather_mean<<<gatherBlocks, 256, 0, stream>>>(xb, rowptr, col, invdeg, meanb, N_NODES);
    transform_kernel<64><<<nodeBlocks, TB, 0, stream>>>(x, meanb, W1l, b1, W1r, hf, hb, N_NODES);

    // ---- layer 2 ----
    gather_mean<<<gatherBlocks, 256, 0, stream>>>(hb, rowptr, col, invdeg, meanb, N_NODES);
    transform_kernel<64><<<nodeBlocks, TB, 0, stream>>>(hf, meanb, W2l, b2, W2r, hf, hb, N_NODES);

    // ---- layer 3 + head ----
    gather_mean<<<gatherBlocks, 256, 0, stream>>>(hb, rowptr, col, invdeg, meanb, N_NODES);
    transform3_kernel<<<nodeBlocks, TB, 0, stream>>>(hf, meanb, W3l, b3, W3r, Wreg, breg, out, N_NODES);
}

// Round 4
// 450.985 us; speedup vs baseline: 5.1571x; 1.1194x over previous
//
#include <hip/hip_runtime.h>
#include <math.h>

#define N_NODES 100000
#define N_EDGES 1600000
#define NB 782              // ceil(N_NODES / 128) buckets, bucket = dst >> 7

typedef unsigned int uint;

__device__ inline ushort f2bf(float f) {
    uint u = __float_as_uint(f);
    uint r = (u + 0x7fffu + ((u >> 16) & 1u)) >> 16;
    return (ushort)r;
}
__device__ inline uint pack2bf(float lo, float hi) {
    return (uint)f2bf(lo) | ((uint)f2bf(hi) << 16);
}

// ---------------- cast x -> bf16 ----------------
__global__ void cast_bf16(const float* __restrict__ in, ushort* __restrict__ out, int n4) {
    int i = blockIdx.x * blockDim.x + threadIdx.x;
    if (i < n4) {
        float4 v = ((const float4*)in)[i];
        uint2 o;
        o.x = pack2bf(v.x, v.y);
        o.y = pack2bf(v.z, v.w);
        ((uint2*)out)[i] = o;
    }
}

// ---------------- CSR build: degree + scan ----------------
__global__ void hist_kernel(const int* __restrict__ dst, int* __restrict__ cnt, int nE) {
    int e = blockIdx.x * blockDim.x + threadIdx.x;
    if (e < nE) atomicAdd(&cnt[dst[e]], 1);
}

__global__ void scan_chunk(const int* __restrict__ in, int* __restrict__ partial,
                           int* __restrict__ sums, int n) {
    __shared__ int s[256];
    int gid = blockIdx.x * 256 + threadIdx.x;
    int v = (gid < n) ? in[gid] : 0;
    s[threadIdx.x] = v;
    __syncthreads();
    for (int off = 1; off < 256; off <<= 1) {
        int t = (threadIdx.x >= (unsigned)off) ? s[threadIdx.x - off] : 0;
        __syncthreads();
        s[threadIdx.x] += t;
        __syncthreads();
    }
    if (gid < n) partial[gid] = s[threadIdx.x];
    if (threadIdx.x == 255) sums[blockIdx.x] = s[255];
}

__global__ void scan_sums(int* __restrict__ sums, int nsums) {
    __shared__ int s[512];
    int tid = threadIdx.x;
    int v = (tid < nsums) ? sums[tid] : 0;
    s[tid] = v;
    __syncthreads();
    for (int off = 1; off < 512; off <<= 1) {
        int t = (tid >= off) ? s[tid - off] : 0;
        __syncthreads();
        s[tid] += t;
        __syncthreads();
    }
    if (tid < nsums) sums[tid] = s[tid];
}

__global__ void finalize_rowptr(const int* __restrict__ partial, const int* __restrict__ sums,
                                int* __restrict__ rowptr, int n) {
    int gid = blockIdx.x * 256 + threadIdx.x;
    if (gid < n) {
        int base = (blockIdx.x > 0) ? sums[blockIdx.x - 1] : 0;
        rowptr[gid + 1] = partial[gid] + base;
        if (gid == 0) rowptr[0] = 0;
    }
}

__global__ void invdeg_rowptr(const int* __restrict__ rowptr, float* __restrict__ invdeg, int n) {
    int gid = blockIdx.x * blockDim.x + threadIdx.x;
    if (gid < n) {
        int d = rowptr[gid + 1] - rowptr[gid];
        invdeg[gid] = 1.0f / fmaxf((float)d, 1.0f);
    }
}

// ---------------- bucketed two-phase fill ----------------
__global__ void init_cursor(const int* __restrict__ rowptr, int* __restrict__ cursor, int nb) {
    int b = blockIdx.x * blockDim.x + threadIdx.x;
    if (b < nb) cursor[b] = rowptr[b << 7];
}

// phase 1: partition edges into 782 bucket regions (block-local runs -> L2-merged writes)
__global__ void partition_kernel(const int* __restrict__ src, const int* __restrict__ dst,
                                 int* __restrict__ cursor, int* __restrict__ part, int nE) {
    __shared__ int hist[NB];
    __shared__ int base[NB];
    __shared__ int rank[NB];
    const int PER = (N_EDGES + 255) / 256;   // 6250 edges per block, 256 blocks
    int e0 = blockIdx.x * PER;
    int e1 = min(e0 + PER, nE);
    for (int i = threadIdx.x; i < NB; i += 256) { hist[i] = 0; rank[i] = 0; }
    __syncthreads();
    for (int e = e0 + threadIdx.x; e < e1; e += 256)
        atomicAdd(&hist[dst[e] >> 7], 1);
    __syncthreads();
    for (int i = threadIdx.x; i < NB; i += 256) {
        int c = hist[i];
        base[i] = c ? atomicAdd(&cursor[i], c) : 0;
    }
    __syncthreads();
    for (int e = e0 + threadIdx.x; e < e1; e += 256) {
        int d = dst[e];
        int bk = d >> 7;
        int r = atomicAdd(&rank[bk], 1);
        part[base[bk] + r] = src[e] | ((d & 127) << 20);
    }
}

// phase 2: one block per bucket; exact CSR slots via LDS counters; writes stay in an ~8KB region
__global__ void bucket_fill(const int* __restrict__ rowptr, const int* __restrict__ part,
                            int* __restrict__ col, int n) {
    __shared__ int rp[129];
    __shared__ int cnt[128];
    int b = blockIdx.x;
    int d0 = b << 7;
    int dl = min(128, n - d0);
    if (threadIdx.x <= (unsigned)dl) rp[threadIdx.x] = rowptr[d0 + threadIdx.x];
    if (threadIdx.x < 128) cnt[threadIdx.x] = 0;
    __syncthreads();
    int ebeg = rp[0], eend = rp[dl];
    for (int i = ebeg + (int)threadIdx.x; i < eend; i += 256) {
        int v = part[i];
        int doff = v >> 20;
        int pos = rp[doff] + atomicAdd(&cnt[doff], 1);
        col[pos] = v & 0xFFFFF;
    }
}

// ---------------- gather mean (64 bf16 features): wave per node, 4 edges per VMEM ----------------
__global__ void gather_mean(const ushort* __restrict__ xb, const int* __restrict__ rowptr,
                            const int* __restrict__ col, const float* __restrict__ invdeg,
                            ushort* __restrict__ meanb, int n) {
    int wave = threadIdx.x >> 6;
    int lane = threadIdx.x & 63;
    int node = blockIdx.x * 4 + wave;
    if (node >= n) return;
    int beg = rowptr[node];
    int end = rowptr[node + 1];
    int grp = lane >> 4;
    int fb = (lane & 15) * 4;
    float a0 = 0.0f, a1 = 0.0f, a2 = 0.0f, a3 = 0.0f;
    for (int i = beg; i < end; i += 64) {
        int idx = i + lane;
        int ci = (idx < end) ? col[idx] : 0;
        int cnt = min(64, end - i);
        int nq = (cnt + 3) >> 2;
#pragma unroll 4
        for (int t = 0; t < nq; ++t) {
            int e = t * 4 + grp;
            int s = __shfl(ci, e, 64);
            if (e < cnt) {
                uint2 w = *(const uint2*)(xb + (size_t)s * 64 + fb);
                a0 += __uint_as_float(w.x << 16);
                a1 += __uint_as_float(w.x & 0xffff0000u);
                a2 += __uint_as_float(w.y << 16);
                a3 += __uint_as_float(w.y & 0xffff0000u);
            }
        }
    }
    a0 += __shfl_xor(a0, 16, 64); a0 += __shfl_xor(a0, 32, 64);
    a1 += __shfl_xor(a1, 16, 64); a1 += __shfl_xor(a1, 32, 64);
    a2 += __shfl_xor(a2, 16, 64); a2 += __shfl_xor(a2, 32, 64);
    a3 += __shfl_xor(a3, 16, 64); a3 += __shfl_xor(a3, 32, 64);
    if (grp == 0) {
        float id = invdeg[node];
        uint2 o;
        o.x = pack2bf(a0 * id, a1 * id);
        o.y = pack2bf(a2 * id, a3 * id);
        *(uint2*)(meanb + (size_t)node * 64 + fb) = o;
    }
}

// ---------------- gather mean (32 bf16 features, for pre-transformed layer 3) ----------------
__global__ void gather_mean32(const ushort* __restrict__ gb, const int* __restrict__ rowptr,
                              const int* __restrict__ col, const float* __restrict__ invdeg,
                              ushort* __restrict__ mean32b, int n) {
    int wave = threadIdx.x >> 6;
    int lane = threadIdx.x & 63;
    int node = blockIdx.x * 4 + wave;
    if (node >= n) return;
    int beg = rowptr[node];
    int end = rowptr[node + 1];
    int grp = lane >> 4;
    int fb = (lane & 15) * 2;
    float a0 = 0.0f, a1 = 0.0f;
    for (int i = beg; i < end; i += 64) {
        int idx = i + lane;
        int ci = (idx < end) ? col[idx] : 0;
        int cnt = min(64, end - i);
        int nq = (cnt + 3) >> 2;
#pragma unroll 4
        for (int t = 0; t < nq; ++t) {
            int e = t * 4 + grp;
            int s = __shfl(ci, e, 64);
            if (e < cnt) {
                uint w = *(const uint*)(gb + (size_t)s * 32 + fb);
                a0 += __uint_as_float(w << 16);
                a1 += __uint_as_float(w & 0xffff0000u);
            }
        }
    }
    a0 += __shfl_xor(a0, 16, 64); a0 += __shfl_xor(a0, 32, 64);
    a1 += __shfl_xor(a1, 16, 64); a1 += __shfl_xor(a1, 32, 64);
    if (grp == 0) {
        float id = invdeg[node];
        *(uint*)(mean32b + (size_t)node * 32 + fb) = pack2bf(a0 * id, a1 * id);
    }
}

// ---------------- transform (layers 1,2): out = relu(mean@Wl.T + b + x@Wr.T) ----------------
template <int DOUT>
__global__ void transform_kernel(const float* __restrict__ xroot, const ushort* __restrict__ meanb,
                                 const float* __restrict__ Wl, const float* __restrict__ b,
                                 const float* __restrict__ Wr,
                                 float* __restrict__ outf, ushort* __restrict__ outb, int n) {
    __shared__ __align__(16) float sWl[DOUT * 64];
    __shared__ __align__(16) float sWr[DOUT * 64];
    __shared__ float sb[DOUT];
    for (int i = threadIdx.x; i < DOUT * 64; i += blockDim.x) {
        sWl[i] = Wl[i];
        sWr[i] = Wr[i];
    }
    for (int i = threadIdx.x; i < DOUT; i += blockDim.x) sb[i] = b[i];
    __syncthreads();

    int node = blockIdx.x * blockDim.x + threadIdx.x;
    if (node >= n) return;

    const float4* xp = (const float4*)(xroot + (size_t)node * 64);
    const uint2* mp = (const uint2*)(meanb + (size_t)node * 64);

    float acc[DOUT];
#pragma unroll
    for (int j = 0; j < DOUT; ++j) acc[j] = sb[j];

#pragma unroll 1
    for (int kk = 0; kk < 16; ++kk) {
        float4 xv = xp[kk];
        uint2 mw = mp[kk];
        float4 mv;
        mv.x = __uint_as_float(mw.x << 16);
        mv.y = __uint_as_float(mw.x & 0xffff0000u);
        mv.z = __uint_as_float(mw.y << 16);
        mv.w = __uint_as_float(mw.y & 0xffff0000u);
#pragma unroll
        for (int j = 0; j < DOUT; ++j) {
            const float4 wl = *(const float4*)&sWl[j * 64 + kk * 4];
            const float4 wr = *(const float4*)&sWr[j * 64 + kk * 4];
            float a = acc[j];
            a = fmaf(mv.x, wl.x, a); a = fmaf(mv.y, wl.y, a);
            a = fmaf(mv.z, wl.z, a); a = fmaf(mv.w, wl.w, a);
            a = fmaf(xv.x, wr.x, a); a = fmaf(xv.y, wr.y, a);
            a = fmaf(xv.z, wr.z, a); a = fmaf(xv.w, wr.w, a);
            acc[j] = a;
        }
    }

#pragma unroll
    for (int j = 0; j < DOUT; ++j) acc[j] = fmaxf(acc[j], 0.0f);

    float4* op = (float4*)(outf + (size_t)node * DOUT);
#pragma unroll
    for (int q = 0; q < DOUT / 4; ++q) {
        float4 o;
        o.x = acc[4 * q + 0]; o.y = acc[4 * q + 1];
        o.z = acc[4 * q + 2]; o.w = acc[4 * q + 3];
        op[q] = o;
    }
    uint4* obp = (uint4*)(outb + (size_t)node * DOUT);
#pragma unroll
    for (int q = 0; q < DOUT / 8; ++q) {
        uint4 o;
        o.x = pack2bf(acc[8 * q + 0], acc[8 * q + 1]);
        o.y = pack2bf(acc[8 * q + 2], acc[8 * q + 3]);
        o.z = pack2bf(acc[8 * q + 4], acc[8 * q + 5]);
        o.w = pack2bf(acc[8 * q + 6], acc[8 * q + 7]);
        obp[q] = o;
    }
}

// ---------------- pre-transform for layer 3: g = h @ W3l.T (bf16 in/out, fp32 math) ----------------
__global__ void pretrans3_kernel(const ushort* __restrict__ hb, const float* __restrict__ Wl,
                                 ushort* __restrict__ gb, int n) {
    __shared__ __align__(16) float sW[32 * 64];
    for (int i = threadIdx.x; i < 32 * 64; i += blockDim.x) sW[i] = Wl[i];
    __syncthreads();

    int node = blockIdx.x * blockDim.x + threadIdx.x;
    if (node >= n) return;

    const uint2* hp = (const uint2*)(hb + (size_t)node * 64);
    float acc[32];
#pragma unroll
    for (int j = 0; j < 32; ++j) acc[j] = 0.0f;

#pragma unroll 1
    for (int kk = 0; kk < 16; ++kk) {
        uint2 hw = hp[kk];
        float4 hv;
        hv.x = __uint_as_float(hw.x << 16);
        hv.y = __uint_as_float(hw.x & 0xffff0000u);
        hv.z = __uint_as_float(hw.y << 16);
        hv.w = __uint_as_float(hw.y & 0xffff0000u);
#pragma unroll
        for (int j = 0; j < 32; ++j) {
            const float4 wl = *(const float4*)&sW[j * 64 + kk * 4];
            float a = acc[j];
            a = fmaf(hv.x, wl.x, a); a = fmaf(hv.y, wl.y, a);
            a = fmaf(hv.z, wl.z, a); a = fmaf(hv.w, wl.w, a);
            acc[j] = a;
        }
    }

    uint4* gp = (uint4*)(gb + (size_t)node * 32);
#pragma unroll
    for (int q = 0; q < 4; ++q) {
        uint4 o;
        o.x = pack2bf(acc[8 * q + 0], acc[8 * q + 1]);
        o.y = pack2bf(acc[8 * q + 2], acc[8 * q + 3]);
        o.z = pack2bf(acc[8 * q + 4], acc[8 * q + 5]);
        o.w = pack2bf(acc[8 * q + 6], acc[8 * q + 7]);
        gp[q] = o;
    }
}

// ---------------- layer 3 + head: out = relu(mean(g) + b3 + h@W3r.T) . Wreg + breg ----------------
__global__ void transform3_kernel(const float* __restrict__ xroot, const ushort* __restrict__ mean32b,
                                  const float* __restrict__ Wr, const float* __restrict__ b,
                                  const float* __restrict__ Wreg, const float* __restrict__ breg,
                                  float* __restrict__ out, int n) {
    __shared__ __align__(16) float sWr[32 * 64];
    __shared__ float sb[32];
    __shared__ float sWreg[32];
    for (int i = threadIdx.x; i < 32 * 64; i += blockDim.x) sWr[i] = Wr[i];
    if (threadIdx.x < 32) {
        sb[threadIdx.x] = b[threadIdx.x];
        sWreg[threadIdx.x] = Wreg[threadIdx.x];
    }
    __syncthreads();

    int node = blockIdx.x * blockDim.x + threadIdx.x;
    if (node >= n) return;

    const float4* xp = (const float4*)(xroot + (size_t)node * 64);
    const uint* mp = (const uint*)(mean32b + (size_t)node * 32);

    float acc[32];
#pragma unroll
    for (int q = 0; q < 16; ++q) {
        uint w = mp[q];
        acc[2 * q + 0] = sb[2 * q + 0] + __uint_as_float(w << 16);
        acc[2 * q + 1] = sb[2 * q + 1] + __uint_as_float(w & 0xffff0000u);
    }

#pragma unroll 1
    for (int kk = 0; kk < 16; ++kk) {
        float4 xv = xp[kk];
#pragma unroll
        for (int j = 0; j < 32; ++j) {
            const float4 wr = *(const float4*)&sWr[j * 64 + kk * 4];
            float a = acc[j];
            a = fmaf(xv.x, wr.x, a); a = fmaf(xv.y, wr.y, a);
            a = fmaf(xv.z, wr.z, a); a = fmaf(xv.w, wr.w, a);
            acc[j] = a;
        }
    }

    float result = breg[0];
#pragma unroll
    for (int j = 0; j < 32; ++j) result = fmaf(fmaxf(acc[j], 0.0f), sWreg[j], result);
    out[node] = result;
}

extern "C" void kernel_launch(void* const* d_in, const int* in_sizes, int n_in,
                              void* d_out, int out_size, void* d_ws, size_t ws_size,
                              hipStream_t stream) {
    const float* x    = (const float*)d_in[0];
    const int*   ei   = (const int*)d_in[1];
    const float* W1l  = (const float*)d_in[2];
    const float* b1   = (const float*)d_in[3];
    const float* W1r  = (const float*)d_in[4];
    const float* W2l  = (const float*)d_in[5];
    const float* b2   = (const float*)d_in[6];
    const float* W2r  = (const float*)d_in[7];
    const float* W3l  = (const float*)d_in[8];
    const float* b3   = (const float*)d_in[9];
    const float* W3r  = (const float*)d_in[10];
    const float* Wreg = (const float*)d_in[11];
    const float* breg = (const float*)d_in[12];

    const int* src = ei;
    const int* dst = ei + N_EDGES;

    char* p = (char*)d_ws;
    auto alloc = [&](size_t bytes) {
        char* r = p;
        p += (bytes + 255) & ~(size_t)255;
        return r;
    };
    int*    degcnt = (int*)alloc(N_NODES * sizeof(int));
    int*    rowptr = (int*)alloc((N_NODES + 1) * sizeof(int));
    int*    partial= (int*)alloc(N_NODES * sizeof(int));
    int*    sums   = (int*)alloc(512 * sizeof(int));
    int*    cursor = (int*)alloc(NB * sizeof(int));
    int*    col    = (int*)alloc((size_t)N_EDGES * sizeof(int));
    float*  invdeg = (float*)alloc(N_NODES * sizeof(float));
    // shared slot: part (6.4MB) -> xb (12.8MB) -> gb (6.4MB); lifetimes don't overlap
    char*   slot   = (char*)alloc((size_t)N_NODES * 64 * sizeof(ushort));
    int*    part   = (int*)slot;
    ushort* xb     = (ushort*)slot;
    ushort* gb     = (ushort*)slot;
    ushort* meanb  = (ushort*)alloc((size_t)N_NODES * 64 * sizeof(ushort)); // also mean32b
    ushort* mean32b= meanb;
    ushort* hb     = (ushort*)alloc((size_t)N_NODES * 64 * sizeof(ushort));
    float*  hf     = (float*)alloc((size_t)N_NODES * 64 * sizeof(float));
    float*  out    = (float*)d_out;

    const int TB = 256;
    int edgeBlocks   = (N_EDGES + TB - 1) / TB;
    int nodeBlocks   = (N_NODES + TB - 1) / TB;
    int gatherBlocks = (N_NODES + 3) / 4;
    int castBlocks   = ((N_NODES * 64 / 4) + TB - 1) / TB;

    // ---- CSR build ----
    hipMemsetAsync(degcnt, 0, N_NODES * sizeof(int), stream);
    hist_kernel<<<edgeBlocks, TB, 0, stream>>>(dst, degcnt, N_EDGES);
    scan_chunk<<<nodeBlocks, 256, 0, stream>>>(degcnt, partial, sums, N_NODES);
    scan_sums<<<1, 512, 0, stream>>>(sums, nodeBlocks);
    finalize_rowptr<<<nodeBlocks, 256, 0, stream>>>(partial, sums, rowptr, N_NODES);
    invdeg_rowptr<<<nodeBlocks, TB, 0, stream>>>(rowptr, invdeg, N_NODES);
    init_cursor<<<(NB + TB - 1) / TB, TB, 0, stream>>>(rowptr, cursor, NB);
    partition_kernel<<<256, 256, 0, stream>>>(src, dst, cursor, part, N_EDGES);
    bucket_fill<<<NB, 256, 0, stream>>>(rowptr, part, col, N_NODES);
    cast_bf16<<<castBlocks, TB, 0, stream>>>(x, xb, N_NODES * 64 / 4);  // after bucket_fill: xb aliases part

    // ---- layer 1 ----
    gather_mean<<<gatherBlocks, 256, 0, stream>>>(xb, rowptr, col, invdeg, meanb, N_NODES);
    transform_kernel<64><<<nodeBlocks, TB, 0, stream>>>(x, meanb, W1l, b1, W1r, hf, hb, N_NODES);

    // ---- layer 2 ----
    gather_mean<<<gatherBlocks, 256, 0, stream>>>(hb, rowptr, col, invdeg, meanb, N_NODES);
    transform_kernel<64><<<nodeBlocks, TB, 0, stream>>>(hf, meanb, W2l, b2, W2r, hf, hb, N_NODES);

    // ---- layer 3: pre-transform, 32-wide gather, fused head ----
    pretrans3_kernel<<<nodeBlocks, TB, 0, stream>>>(hb, W3l, gb, N_NODES);   // gb aliases xb (dead)
    gather_mean32<<<gatherBlocks, 256, 0, stream>>>(gb, rowptr, col, invdeg, mean32b, N_NODES);
    transform3_kernel<<<nodeBlocks, TB, 0, stream>>>(hf, mean32b, W3r, b3, Wreg, breg, out, N_NODES);
}

// Round 5
// 432.049 us; speedup vs baseline: 5.3831x; 1.0438x over previous
//
#include <hip/hip_runtime.h>
#include <math.h>

#define N_NODES 100000
#define N_EDGES 1600000
#define NB 782              // ceil(N_NODES / 128) buckets, bucket = dst >> 7

typedef unsigned int uint;

__device__ inline ushort f2bf(float f) {
    uint u = __float_as_uint(f);
    uint r = (u + 0x7fffu + ((u >> 16) & 1u)) >> 16;
    return (ushort)r;
}
__device__ inline uint pack2bf(float lo, float hi) {
    return (uint)f2bf(lo) | ((uint)f2bf(hi) << 16);
}

// ---------------- cast x -> bf16 ----------------
__global__ void cast_bf16(const float* __restrict__ in, ushort* __restrict__ out, int n4) {
    int i = blockIdx.x * blockDim.x + threadIdx.x;
    if (i < n4) {
        float4 v = ((const float4*)in)[i];
        uint2 o;
        o.x = pack2bf(v.x, v.y);
        o.y = pack2bf(v.z, v.w);
        ((uint2*)out)[i] = o;
    }
}

// ---------------- CSR build: degree + scan ----------------
__global__ void hist_kernel(const int* __restrict__ dst, int* __restrict__ cnt, int nE) {
    int e = blockIdx.x * blockDim.x + threadIdx.x;
    if (e < nE) atomicAdd(&cnt[dst[e]], 1);
}

__global__ void scan_chunk(const int* __restrict__ in, int* __restrict__ partial,
                           int* __restrict__ sums, int n) {
    __shared__ int s[256];
    int gid = blockIdx.x * 256 + threadIdx.x;
    int v = (gid < n) ? in[gid] : 0;
    s[threadIdx.x] = v;
    __syncthreads();
    for (int off = 1; off < 256; off <<= 1) {
        int t = (threadIdx.x >= (unsigned)off) ? s[threadIdx.x - off] : 0;
        __syncthreads();
        s[threadIdx.x] += t;
        __syncthreads();
    }
    if (gid < n) partial[gid] = s[threadIdx.x];
    if (threadIdx.x == 255) sums[blockIdx.x] = s[255];
}

__global__ void scan_sums(int* __restrict__ sums, int nsums) {
    __shared__ int s[512];
    int tid = threadIdx.x;
    int v = (tid < nsums) ? sums[tid] : 0;
    s[tid] = v;
    __syncthreads();
    for (int off = 1; off < 512; off <<= 1) {
        int t = (tid >= off) ? s[tid - off] : 0;
        __syncthreads();
        s[tid] += t;
        __syncthreads();
    }
    if (tid < nsums) sums[tid] = s[tid];
}

__global__ void finalize_rowptr(const int* __restrict__ partial, const int* __restrict__ sums,
                                int* __restrict__ rowptr, int n) {
    int gid = blockIdx.x * 256 + threadIdx.x;
    if (gid < n) {
        int base = (blockIdx.x > 0) ? sums[blockIdx.x - 1] : 0;
        rowptr[gid + 1] = partial[gid] + base;
        if (gid == 0) rowptr[0] = 0;
    }
}

__global__ void invdeg_rowptr(const int* __restrict__ rowptr, float* __restrict__ invdeg, int n) {
    int gid = blockIdx.x * blockDim.x + threadIdx.x;
    if (gid < n) {
        int d = rowptr[gid + 1] - rowptr[gid];
        invdeg[gid] = 1.0f / fmaxf((float)d, 1.0f);
    }
}

// ---------------- bucketed two-phase fill ----------------
__global__ void init_cursor(const int* __restrict__ rowptr, int* __restrict__ cursor, int nb) {
    int b = blockIdx.x * blockDim.x + threadIdx.x;
    if (b < nb) cursor[b] = rowptr[b << 7];
}

__global__ void partition_kernel(const int* __restrict__ src, const int* __restrict__ dst,
                                 int* __restrict__ cursor, int* __restrict__ part, int nE) {
    __shared__ int hist[NB];
    __shared__ int base[NB];
    __shared__ int rank[NB];
    const int PER = (N_EDGES + 255) / 256;
    int e0 = blockIdx.x * PER;
    int e1 = min(e0 + PER, nE);
    for (int i = threadIdx.x; i < NB; i += 256) { hist[i] = 0; rank[i] = 0; }
    __syncthreads();
    for (int e = e0 + threadIdx.x; e < e1; e += 256)
        atomicAdd(&hist[dst[e] >> 7], 1);
    __syncthreads();
    for (int i = threadIdx.x; i < NB; i += 256) {
        int c = hist[i];
        base[i] = c ? atomicAdd(&cursor[i], c) : 0;
    }
    __syncthreads();
    for (int e = e0 + threadIdx.x; e < e1; e += 256) {
        int d = dst[e];
        int bk = d >> 7;
        int r = atomicAdd(&rank[bk], 1);
        part[base[bk] + r] = src[e] | ((d & 127) << 20);
    }
}

__global__ void bucket_fill(const int* __restrict__ rowptr, const int* __restrict__ part,
                            int* __restrict__ col, int n) {
    __shared__ int rp[129];
    __shared__ int cnt[128];
    int b = blockIdx.x;
    int d0 = b << 7;
    int dl = min(128, n - d0);
    if (threadIdx.x <= (unsigned)dl) rp[threadIdx.x] = rowptr[d0 + threadIdx.x];
    if (threadIdx.x < 128) cnt[threadIdx.x] = 0;
    __syncthreads();
    int ebeg = rp[0], eend = rp[dl];
    for (int i = ebeg + (int)threadIdx.x; i < eend; i += 256) {
        int v = part[i];
        int doff = v >> 20;
        int pos = rp[doff] + atomicAdd(&cnt[doff], 1);
        col[pos] = v & 0xFFFFF;
    }
}

// ---------------- gather mean (64 bf16 features): wave per node, 4 edges per VMEM ----------------
__global__ void gather_mean(const ushort* __restrict__ xb, const int* __restrict__ rowptr,
                            const int* __restrict__ col, const float* __restrict__ invdeg,
                            ushort* __restrict__ meanb, int n) {
    int wave = threadIdx.x >> 6;
    int lane = threadIdx.x & 63;
    int node = blockIdx.x * 4 + wave;
    if (node >= n) return;
    int beg = rowptr[node];
    int end = rowptr[node + 1];
    int grp = lane >> 4;
    int fb = (lane & 15) * 4;
    float a0 = 0.0f, a1 = 0.0f, a2 = 0.0f, a3 = 0.0f;
    for (int i = beg; i < end; i += 64) {
        int idx = i + lane;
        int ci = (idx < end) ? col[idx] : 0;
        int cnt = min(64, end - i);
        int nq = (cnt + 3) >> 2;
#pragma unroll 4
        for (int t = 0; t < nq; ++t) {
            int e = t * 4 + grp;
            int s = __shfl(ci, e, 64);
            if (e < cnt) {
                uint2 w = *(const uint2*)(xb + (size_t)s * 64 + fb);
                a0 += __uint_as_float(w.x << 16);
                a1 += __uint_as_float(w.x & 0xffff0000u);
                a2 += __uint_as_float(w.y << 16);
                a3 += __uint_as_float(w.y & 0xffff0000u);
            }
        }
    }
    a0 += __shfl_xor(a0, 16, 64); a0 += __shfl_xor(a0, 32, 64);
    a1 += __shfl_xor(a1, 16, 64); a1 += __shfl_xor(a1, 32, 64);
    a2 += __shfl_xor(a2, 16, 64); a2 += __shfl_xor(a2, 32, 64);
    a3 += __shfl_xor(a3, 16, 64); a3 += __shfl_xor(a3, 32, 64);
    if (grp == 0) {
        float id = invdeg[node];
        uint2 o;
        o.x = pack2bf(a0 * id, a1 * id);
        o.y = pack2bf(a2 * id, a3 * id);
        *(uint2*)(meanb + (size_t)node * 64 + fb) = o;
    }
}

// ---------------- gather mean (32 bf16 features, pre-transformed layer 3) ----------------
__global__ void gather_mean32(const ushort* __restrict__ gb, const int* __restrict__ rowptr,
                              const int* __restrict__ col, const float* __restrict__ invdeg,
                              ushort* __restrict__ mean32b, int n) {
    int wave = threadIdx.x >> 6;
    int lane = threadIdx.x & 63;
    int node = blockIdx.x * 4 + wave;
    if (node >= n) return;
    int beg = rowptr[node];
    int end = rowptr[node + 1];
    int grp = lane >> 4;
    int fb = (lane & 15) * 2;
    float a0 = 0.0f, a1 = 0.0f;
    for (int i = beg; i < end; i += 64) {
        int idx = i + lane;
        int ci = (idx < end) ? col[idx] : 0;
        int cnt = min(64, end - i);
        int nq = (cnt + 3) >> 2;
#pragma unroll 4
        for (int t = 0; t < nq; ++t) {
            int e = t * 4 + grp;
            int s = __shfl(ci, e, 64);
            if (e < cnt) {
                uint w = *(const uint*)(gb + (size_t)s * 32 + fb);
                a0 += __uint_as_float(w << 16);
                a1 += __uint_as_float(w & 0xffff0000u);
            }
        }
    }
    a0 += __shfl_xor(a0, 16, 64); a0 += __shfl_xor(a0, 32, 64);
    a1 += __shfl_xor(a1, 16, 64); a1 += __shfl_xor(a1, 32, 64);
    if (grp == 0) {
        float id = invdeg[node];
        *(uint*)(mean32b + (size_t)node * 32 + fb) = pack2bf(a0 * id, a1 * id);
    }
}

// ---------------- transform (layers 1,2): h = relu(mean@Wl.T + b + x@Wr.T), all-bf16 I/O ----------------
template <int DOUT>
__global__ void __launch_bounds__(256, 2)
transform_kernel(const ushort* __restrict__ xrootb, const ushort* __restrict__ meanb,
                 const float* __restrict__ Wl, const float* __restrict__ b,
                 const float* __restrict__ Wr,
                 ushort* __restrict__ outb, int n) {
    __shared__ __align__(16) float sWl[DOUT * 64];
    __shared__ __align__(16) float sWr[DOUT * 64];
    __shared__ float sb[DOUT];
    for (int i = threadIdx.x; i < DOUT * 64; i += blockDim.x) {
        sWl[i] = Wl[i];
        sWr[i] = Wr[i];
    }
    for (int i = threadIdx.x; i < DOUT; i += blockDim.x) sb[i] = b[i];
    __syncthreads();

    int node = blockIdx.x * blockDim.x + threadIdx.x;
    if (node >= n) return;

    const uint2* xp = (const uint2*)(xrootb + (size_t)node * 64);
    const uint2* mp = (const uint2*)(meanb + (size_t)node * 64);

    float acc[DOUT];
#pragma unroll
    for (int j = 0; j < DOUT; ++j) acc[j] = sb[j];

#pragma unroll 1
    for (int kk = 0; kk < 16; ++kk) {
        uint2 xw = xp[kk];
        uint2 mw = mp[kk];
        float4 xv, mv;
        xv.x = __uint_as_float(xw.x << 16);
        xv.y = __uint_as_float(xw.x & 0xffff0000u);
        xv.z = __uint_as_float(xw.y << 16);
        xv.w = __uint_as_float(xw.y & 0xffff0000u);
        mv.x = __uint_as_float(mw.x << 16);
        mv.y = __uint_as_float(mw.x & 0xffff0000u);
        mv.z = __uint_as_float(mw.y << 16);
        mv.w = __uint_as_float(mw.y & 0xffff0000u);
#pragma unroll
        for (int j = 0; j < DOUT; ++j) {
            const float4 wl = *(const float4*)&sWl[j * 64 + kk * 4];
            const float4 wr = *(const float4*)&sWr[j * 64 + kk * 4];
            float a = acc[j];
            a = fmaf(mv.x, wl.x, a); a = fmaf(mv.y, wl.y, a);
            a = fmaf(mv.z, wl.z, a); a = fmaf(mv.w, wl.w, a);
            a = fmaf(xv.x, wr.x, a); a = fmaf(xv.y, wr.y, a);
            a = fmaf(xv.z, wr.z, a); a = fmaf(xv.w, wr.w, a);
            acc[j] = a;
        }
    }

#pragma unroll
    for (int j = 0; j < DOUT; ++j) acc[j] = fmaxf(acc[j], 0.0f);

    uint4* obp = (uint4*)(outb + (size_t)node * DOUT);
#pragma unroll
    for (int q = 0; q < DOUT / 8; ++q) {
        uint4 o;
        o.x = pack2bf(acc[8 * q + 0], acc[8 * q + 1]);
        o.y = pack2bf(acc[8 * q + 2], acc[8 * q + 3]);
        o.z = pack2bf(acc[8 * q + 4], acc[8 * q + 5]);
        o.w = pack2bf(acc[8 * q + 6], acc[8 * q + 7]);
        obp[q] = o;
    }
}

// ---------------- pre-transform for layer 3: g = h @ W3l.T ----------------
__global__ void __launch_bounds__(256, 2)
pretrans3_kernel(const ushort* __restrict__ hb, const float* __restrict__ Wl,
                 ushort* __restrict__ gb, int n) {
    __shared__ __align__(16) float sW[32 * 64];
    for (int i = threadIdx.x; i < 32 * 64; i += blockDim.x) sW[i] = Wl[i];
    __syncthreads();

    int node = blockIdx.x * blockDim.x + threadIdx.x;
    if (node >= n) return;

    const uint2* hp = (const uint2*)(hb + (size_t)node * 64);
    float acc[32];
#pragma unroll
    for (int j = 0; j < 32; ++j) acc[j] = 0.0f;

#pragma unroll 1
    for (int kk = 0; kk < 16; ++kk) {
        uint2 hw = hp[kk];
        float4 hv;
        hv.x = __uint_as_float(hw.x << 16);
        hv.y = __uint_as_float(hw.x & 0xffff0000u);
        hv.z = __uint_as_float(hw.y << 16);
        hv.w = __uint_as_float(hw.y & 0xffff0000u);
#pragma unroll
        for (int j = 0; j < 32; ++j) {
            const float4 wl = *(const float4*)&sW[j * 64 + kk * 4];
            float a = acc[j];
            a = fmaf(hv.x, wl.x, a); a = fmaf(hv.y, wl.y, a);
            a = fmaf(hv.z, wl.z, a); a = fmaf(hv.w, wl.w, a);
            acc[j] = a;
        }
    }

    uint4* gp = (uint4*)(gb + (size_t)node * 32);
#pragma unroll
    for (int q = 0; q < 4; ++q) {
        uint4 o;
        o.x = pack2bf(acc[8 * q + 0], acc[8 * q + 1]);
        o.y = pack2bf(acc[8 * q + 2], acc[8 * q + 3]);
        o.z = pack2bf(acc[8 * q + 4], acc[8 * q + 5]);
        o.w = pack2bf(acc[8 * q + 6], acc[8 * q + 7]);
        gp[q] = o;
    }
}

// ---------------- layer 3 + head ----------------
__global__ void __launch_bounds__(256, 2)
transform3_kernel(const ushort* __restrict__ hrootb, const ushort* __restrict__ mean32b,
                  const float* __restrict__ Wr, const float* __restrict__ b,
                  const float* __restrict__ Wreg, const float* __restrict__ breg,
                  float* __restrict__ out, int n) {
    __shared__ __align__(16) float sWr[32 * 64];
    __shared__ float sb[32];
    __shared__ float sWreg[32];
    for (int i = threadIdx.x; i < 32 * 64; i += blockDim.x) sWr[i] = Wr[i];
    if (threadIdx.x < 32) {
        sb[threadIdx.x] = b[threadIdx.x];
        sWreg[threadIdx.x] = Wreg[threadIdx.x];
    }
    __syncthreads();

    int node = blockIdx.x * blockDim.x + threadIdx.x;
    if (node >= n) return;

    const uint2* xp = (const uint2*)(hrootb + (size_t)node * 64);
    const uint* mp = (const uint*)(mean32b + (size_t)node * 32);

    float acc[32];
#pragma unroll
    for (int q = 0; q < 16; ++q) {
        uint w = mp[q];
        acc[2 * q + 0] = sb[2 * q + 0] + __uint_as_float(w << 16);
        acc[2 * q + 1] = sb[2 * q + 1] + __uint_as_float(w & 0xffff0000u);
    }

#pragma unroll 1
    for (int kk = 0; kk < 16; ++kk) {
        uint2 xw = xp[kk];
        float4 xv;
        xv.x = __uint_as_float(xw.x << 16);
        xv.y = __uint_as_float(xw.x & 0xffff0000u);
        xv.z = __uint_as_float(xw.y << 16);
        xv.w = __uint_as_float(xw.y & 0xffff0000u);
#pragma unroll
        for (int j = 0; j < 32; ++j) {
            const float4 wr = *(const float4*)&sWr[j * 64 + kk * 4];
            float a = acc[j];
            a = fmaf(xv.x, wr.x, a); a = fmaf(xv.y, wr.y, a);
            a = fmaf(xv.z, wr.z, a); a = fmaf(xv.w, wr.w, a);
            acc[j] = a;
        }
    }

    float result = breg[0];
#pragma unroll
    for (int j = 0; j < 32; ++j) result = fmaf(fmaxf(acc[j], 0.0f), sWreg[j], result);
    out[node] = result;
}

extern "C" void kernel_launch(void* const* d_in, const int* in_sizes, int n_in,
                              void* d_out, int out_size, void* d_ws, size_t ws_size,
                              hipStream_t stream) {
    const float* x    = (const float*)d_in[0];
    const int*   ei   = (const int*)d_in[1];
    const float* W1l  = (const float*)d_in[2];
    const float* b1   = (const float*)d_in[3];
    const float* W1r  = (const float*)d_in[4];
    const float* W2l  = (const float*)d_in[5];
    const float* b2   = (const float*)d_in[6];
    const float* W2r  = (const float*)d_in[7];
    const float* W3l  = (const float*)d_in[8];
    const float* b3   = (const float*)d_in[9];
    const float* W3r  = (const float*)d_in[10];
    const float* Wreg = (const float*)d_in[11];
    const float* breg = (const float*)d_in[12];

    const int* src = ei;
    const int* dst = ei + N_EDGES;

    char* p = (char*)d_ws;
    auto alloc = [&](size_t bytes) {
        char* r = p;
        p += (bytes + 255) & ~(size_t)255;
        return r;
    };
    int*    degcnt = (int*)alloc(N_NODES * sizeof(int));
    int*    rowptr = (int*)alloc((N_NODES + 1) * sizeof(int));
    int*    partial= (int*)alloc(N_NODES * sizeof(int));
    int*    sums   = (int*)alloc(512 * sizeof(int));
    int*    cursor = (int*)alloc(NB * sizeof(int));
    int*    col    = (int*)alloc((size_t)N_EDGES * sizeof(int));
    float*  invdeg = (float*)alloc(N_NODES * sizeof(float));
    // shared slot: part (6.4MB) -> xb (12.8MB) -> gb (6.4MB); lifetimes don't overlap
    char*   slot   = (char*)alloc((size_t)N_NODES * 64 * sizeof(ushort));
    int*    part   = (int*)slot;
    ushort* xb     = (ushort*)slot;
    ushort* gb     = (ushort*)slot;
    ushort* meanb  = (ushort*)alloc((size_t)N_NODES * 64 * sizeof(ushort)); // also mean32b
    ushort* mean32b= meanb;
    ushort* hb     = (ushort*)alloc((size_t)N_NODES * 64 * sizeof(ushort));
    float*  out    = (float*)d_out;

    const int TB = 256;
    int edgeBlocks   = (N_EDGES + TB - 1) / TB;
    int nodeBlocks   = (N_NODES + TB - 1) / TB;
    int gatherBlocks = (N_NODES + 3) / 4;
    int castBlocks   = ((N_NODES * 64 / 4) + TB - 1) / TB;

    // ---- CSR build ----
    hipMemsetAsync(degcnt, 0, N_NODES * sizeof(int), stream);
    hist_kernel<<<edgeBlocks, TB, 0, stream>>>(dst, degcnt, N_EDGES);
    scan_chunk<<<nodeBlocks, 256, 0, stream>>>(degcnt, partial, sums, N_NODES);
    scan_sums<<<1, 512, 0, stream>>>(sums, nodeBlocks);
    finalize_rowptr<<<nodeBlocks, 256, 0, stream>>>(partial, sums, rowptr, N_NODES);
    invdeg_rowptr<<<nodeBlocks, TB, 0, stream>>>(rowptr, invdeg, N_NODES);
    init_cursor<<<(NB + TB - 1) / TB, TB, 0, stream>>>(rowptr, cursor, NB);
    partition_kernel<<<256, 256, 0, stream>>>(src, dst, cursor, part, N_EDGES);
    bucket_fill<<<NB, 256, 0, stream>>>(rowptr, part, col, N_NODES);
    cast_bf16<<<castBlocks, TB, 0, stream>>>(x, xb, N_NODES * 64 / 4);  // after bucket_fill: xb aliases part

    // ---- layer 1 ----
    gather_mean<<<gatherBlocks, 256, 0, stream>>>(xb, rowptr, col, invdeg, meanb, N_NODES);
    transform_kernel<64><<<nodeBlocks, TB, 0, stream>>>(xb, meanb, W1l, b1, W1r, hb, N_NODES);

    // ---- layer 2 ----
    gather_mean<<<gatherBlocks, 256, 0, stream>>>(hb, rowptr, col, invdeg, meanb, N_NODES);
    transform_kernel<64><<<nodeBlocks, TB, 0, stream>>>(hb, meanb, W2l, b2, W2r, hb, N_NODES);

    // ---- layer 3: pre-transform, 32-wide gather, fused head ----
    pretrans3_kernel<<<nodeBlocks, TB, 0, stream>>>(hb, W3l, gb, N_NODES);   // gb aliases xb (dead)
    gather_mean32<<<gatherBlocks, 256, 0, stream>>>(gb, rowptr, col, invdeg, mean32b, N_NODES);
    transform3_kernel<<<nodeBlocks, TB, 0, stream>>>(hb, mean32b, W3r, b3, Wreg, breg, out, N_NODES);
}

// Round 6
// 302.718 us; speedup vs baseline: 7.6830x; 1.4272x over previous
//
#include <hip/hip_runtime.h>
#include <math.h>

#define N_NODES 100000
#define N_EDGES 1600000
#define NB 782              // ceil(N_NODES / 128) buckets, bucket = dst >> 7
#define NTILES 6250         // N_NODES / 16 (exact)

typedef unsigned int uint;
typedef __attribute__((ext_vector_type(8))) short bf16x8;
typedef __attribute__((ext_vector_type(4))) float f32x4;

__device__ inline ushort f2bf(float f) {
    uint u = __float_as_uint(f);
    uint r = (u + 0x7fffu + ((u >> 16) & 1u)) >> 16;
    return (ushort)r;
}
__device__ inline uint pack2bf(float lo, float hi) {
    return (uint)f2bf(lo) | ((uint)f2bf(hi) << 16);
}

// ---------------- cast x -> bf16 ----------------
__global__ void cast_bf16(const float* __restrict__ in, ushort* __restrict__ out, int n4) {
    int i = blockIdx.x * blockDim.x + threadIdx.x;
    if (i < n4) {
        float4 v = ((const float4*)in)[i];
        uint2 o;
        o.x = pack2bf(v.x, v.y);
        o.y = pack2bf(v.z, v.w);
        ((uint2*)out)[i] = o;
    }
}

// ---------------- weight-fragment prep (one-shot, 20480 elems) ----------------
// Layout per frag f: lane l, elem i -> W[k][j], k = ks*32+(l>>4)*8+i, j = nt*16+(l&15),
// f = nt*(KT/32)+ks. Buffer elem index = f*512 + l*8 + i.
// Regions: [0,8192) L1 (K=128: Wl|Wr); [8192,16384) L2; [16384,18432) W3l (K=64); [18432,20480) W3r.
__global__ void prep_wfrag(const float* __restrict__ W1l, const float* __restrict__ W1r,
                           const float* __restrict__ W2l, const float* __restrict__ W2r,
                           const float* __restrict__ W3l, const float* __restrict__ W3r,
                           ushort* __restrict__ wf) {
    int idx = blockIdx.x * 256 + threadIdx.x;
    if (idx >= 20480) return;
    const float *Wl, *Wr;
    int base, KT;
    if (idx < 8192)       { base = 0;     Wl = W1l; Wr = W1r; KT = 128; }
    else if (idx < 16384) { base = 8192;  Wl = W2l; Wr = W2r; KT = 128; }
    else if (idx < 18432) { base = 16384; Wl = W3l; Wr = 0;   KT = 64; }
    else                  { base = 18432; Wl = W3r; Wr = 0;   KT = 64; }
    int r = idx - base;
    int f = r >> 9;
    int l = (r >> 3) & 63;
    int i = r & 7;
    int nks = KT >> 5;
    int nt = f / nks, ks = f - nt * nks;
    int k = ks * 32 + ((l >> 4) << 3) + i;
    int j = nt * 16 + (l & 15);
    float v = (k < 64) ? Wl[j * 64 + k] : Wr[j * 64 + (k - 64)];
    wf[idx] = f2bf(v);
}

// ---------------- CSR build: degree + scan ----------------
__global__ void hist_kernel(const int* __restrict__ dst, int* __restrict__ cnt, int nE) {
    int e = blockIdx.x * blockDim.x + threadIdx.x;
    if (e < nE) atomicAdd(&cnt[dst[e]], 1);
}

__global__ void scan_chunk(const int* __restrict__ in, int* __restrict__ partial,
                           int* __restrict__ sums, int n) {
    __shared__ int s[256];
    int gid = blockIdx.x * 256 + threadIdx.x;
    int v = (gid < n) ? in[gid] : 0;
    s[threadIdx.x] = v;
    __syncthreads();
    for (int off = 1; off < 256; off <<= 1) {
        int t = (threadIdx.x >= (unsigned)off) ? s[threadIdx.x - off] : 0;
        __syncthreads();
        s[threadIdx.x] += t;
        __syncthreads();
    }
    if (gid < n) partial[gid] = s[threadIdx.x];
    if (threadIdx.x == 255) sums[blockIdx.x] = s[255];
}

__global__ void scan_sums(int* __restrict__ sums, int nsums) {
    __shared__ int s[512];
    int tid = threadIdx.x;
    int v = (tid < nsums) ? sums[tid] : 0;
    s[tid] = v;
    __syncthreads();
    for (int off = 1; off < 512; off <<= 1) {
        int t = (tid >= off) ? s[tid - off] : 0;
        __syncthreads();
        s[tid] += t;
        __syncthreads();
    }
    if (tid < nsums) sums[tid] = s[tid];
}

__global__ void finalize_rowptr(const int* __restrict__ partial, const int* __restrict__ sums,
                                int* __restrict__ rowptr, int n) {
    int gid = blockIdx.x * 256 + threadIdx.x;
    if (gid < n) {
        int base = (blockIdx.x > 0) ? sums[blockIdx.x - 1] : 0;
        rowptr[gid + 1] = partial[gid] + base;
        if (gid == 0) rowptr[0] = 0;
    }
}

__global__ void invdeg_rowptr(const int* __restrict__ rowptr, float* __restrict__ invdeg, int n) {
    int gid = blockIdx.x * blockDim.x + threadIdx.x;
    if (gid < n) {
        int d = rowptr[gid + 1] - rowptr[gid];
        invdeg[gid] = 1.0f / fmaxf((float)d, 1.0f);
    }
}

// ---------------- bucketed two-phase fill ----------------
__global__ void init_cursor(const int* __restrict__ rowptr, int* __restrict__ cursor, int nb) {
    int b = blockIdx.x * blockDim.x + threadIdx.x;
    if (b < nb) cursor[b] = rowptr[b << 7];
}

__global__ void partition_kernel(const int* __restrict__ src, const int* __restrict__ dst,
                                 int* __restrict__ cursor, int* __restrict__ part, int nE) {
    __shared__ int hist[NB];
    __shared__ int base[NB];
    __shared__ int rank[NB];
    const int PER = (N_EDGES + 255) / 256;
    int e0 = blockIdx.x * PER;
    int e1 = min(e0 + PER, nE);
    for (int i = threadIdx.x; i < NB; i += 256) { hist[i] = 0; rank[i] = 0; }
    __syncthreads();
    for (int e = e0 + threadIdx.x; e < e1; e += 256)
        atomicAdd(&hist[dst[e] >> 7], 1);
    __syncthreads();
    for (int i = threadIdx.x; i < NB; i += 256) {
        int c = hist[i];
        base[i] = c ? atomicAdd(&cursor[i], c) : 0;
    }
    __syncthreads();
    for (int e = e0 + threadIdx.x; e < e1; e += 256) {
        int d = dst[e];
        int bk = d >> 7;
        int r = atomicAdd(&rank[bk], 1);
        part[base[bk] + r] = src[e] | ((d & 127) << 20);
    }
}

__global__ void bucket_fill(const int* __restrict__ rowptr, const int* __restrict__ part,
                            int* __restrict__ col, int n) {
    __shared__ int rp[129];
    __shared__ int cnt[128];
    int b = blockIdx.x;
    int d0 = b << 7;
    int dl = min(128, n - d0);
    if (threadIdx.x <= (unsigned)dl) rp[threadIdx.x] = rowptr[d0 + threadIdx.x];
    if (threadIdx.x < 128) cnt[threadIdx.x] = 0;
    __syncthreads();
    int ebeg = rp[0], eend = rp[dl];
    for (int i = ebeg + (int)threadIdx.x; i < eend; i += 256) {
        int v = part[i];
        int doff = v >> 20;
        int pos = rp[doff] + atomicAdd(&cnt[doff], 1);
        col[pos] = v & 0xFFFFF;
    }
}

// ---------------- gather mean (64 bf16 features): wave per node, 4 edges per VMEM ----------------
__global__ void gather_mean(const ushort* __restrict__ xb, const int* __restrict__ rowptr,
                            const int* __restrict__ col, const float* __restrict__ invdeg,
                            ushort* __restrict__ meanb, int n) {
    int wave = threadIdx.x >> 6;
    int lane = threadIdx.x & 63;
    int node = blockIdx.x * 4 + wave;
    if (node >= n) return;
    int beg = rowptr[node];
    int end = rowptr[node + 1];
    int grp = lane >> 4;
    int fb = (lane & 15) * 4;
    float a0 = 0.0f, a1 = 0.0f, a2 = 0.0f, a3 = 0.0f;
    for (int i = beg; i < end; i += 64) {
        int idx = i + lane;
        int ci = (idx < end) ? col[idx] : 0;
        int cnt = min(64, end - i);
        int nq = (cnt + 3) >> 2;
#pragma unroll 4
        for (int t = 0; t < nq; ++t) {
            int e = t * 4 + grp;
            int s = __shfl(ci, e, 64);
            if (e < cnt) {
                uint2 w = *(const uint2*)(xb + (size_t)s * 64 + fb);
                a0 += __uint_as_float(w.x << 16);
                a1 += __uint_as_float(w.x & 0xffff0000u);
                a2 += __uint_as_float(w.y << 16);
                a3 += __uint_as_float(w.y & 0xffff0000u);
            }
        }
    }
    a0 += __shfl_xor(a0, 16, 64); a0 += __shfl_xor(a0, 32, 64);
    a1 += __shfl_xor(a1, 16, 64); a1 += __shfl_xor(a1, 32, 64);
    a2 += __shfl_xor(a2, 16, 64); a2 += __shfl_xor(a2, 32, 64);
    a3 += __shfl_xor(a3, 16, 64); a3 += __shfl_xor(a3, 32, 64);
    if (grp == 0) {
        float id = invdeg[node];
        uint2 o;
        o.x = pack2bf(a0 * id, a1 * id);
        o.y = pack2bf(a2 * id, a3 * id);
        *(uint2*)(meanb + (size_t)node * 64 + fb) = o;
    }
}

// ---------------- gather mean (32 bf16 features, pre-transformed layer 3) ----------------
__global__ void gather_mean32(const ushort* __restrict__ gb, const int* __restrict__ rowptr,
                              const int* __restrict__ col, const float* __restrict__ invdeg,
                              ushort* __restrict__ mean32b, int n) {
    int wave = threadIdx.x >> 6;
    int lane = threadIdx.x & 63;
    int node = blockIdx.x * 4 + wave;
    if (node >= n) return;
    int beg = rowptr[node];
    int end = rowptr[node + 1];
    int grp = lane >> 4;
    int fb = (lane & 15) * 2;
    float a0 = 0.0f, a1 = 0.0f;
    for (int i = beg; i < end; i += 64) {
        int idx = i + lane;
        int ci = (idx < end) ? col[idx] : 0;
        int cnt = min(64, end - i);
        int nq = (cnt + 3) >> 2;
#pragma unroll 4
        for (int t = 0; t < nq; ++t) {
            int e = t * 4 + grp;
            int s = __shfl(ci, e, 64);
            if (e < cnt) {
                uint w = *(const uint*)(gb + (size_t)s * 32 + fb);
                a0 += __uint_as_float(w << 16);
                a1 += __uint_as_float(w & 0xffff0000u);
            }
        }
    }
    a0 += __shfl_xor(a0, 16, 64); a0 += __shfl_xor(a0, 32, 64);
    a1 += __shfl_xor(a1, 16, 64); a1 += __shfl_xor(a1, 32, 64);
    if (grp == 0) {
        float id = invdeg[node];
        *(uint*)(mean32b + (size_t)node * 32 + fb) = pack2bf(a0 * id, a1 * id);
    }
}

// ---------------- MFMA transform (layers 1,2): h = relu([mean|x] @ Wcomb + b) ----------------
// Wave processes 16-node tiles; weights in registers (16 frags); K=128, N=64.
__global__ void __launch_bounds__(256)
mfma_transform(const ushort* __restrict__ rootb, const ushort* __restrict__ meanb,
               const ushort* __restrict__ wfrag, const float* __restrict__ bias,
               ushort* __restrict__ outb, int ntiles) {
    int wave = threadIdx.x >> 6;
    int lane = threadIdx.x & 63;

    bf16x8 wf[4][4];
#pragma unroll
    for (int nt = 0; nt < 4; ++nt)
#pragma unroll
        for (int ks = 0; ks < 4; ++ks)
            wf[nt][ks] = *(const bf16x8*)(wfrag + (size_t)((nt * 4 + ks) * 64 + lane) * 8);

    float bl[4];
#pragma unroll
    for (int nt = 0; nt < 4; ++nt) bl[nt] = bias[nt * 16 + (lane & 15)];

    int arow = lane & 15;          // A-frag row within tile
    int koff = (lane >> 4) * 8;    // k-offset within 32-wide step
    int crow = (lane >> 4) * 4;    // C rows base
    int nwaves = gridDim.x * 4;

    for (int tile = blockIdx.x * 4 + wave; tile < ntiles; tile += nwaves) {
        int n0 = tile * 16;
        const ushort* mrow = meanb + (size_t)(n0 + arow) * 64 + koff;
        const ushort* xrow = rootb + (size_t)(n0 + arow) * 64 + koff;
        bf16x8 a0 = *(const bf16x8*)(mrow);
        bf16x8 a1 = *(const bf16x8*)(mrow + 32);
        bf16x8 a2 = *(const bf16x8*)(xrow);
        bf16x8 a3 = *(const bf16x8*)(xrow + 32);
#pragma unroll
        for (int nt = 0; nt < 4; ++nt) {
            f32x4 c = {0.f, 0.f, 0.f, 0.f};
            c = __builtin_amdgcn_mfma_f32_16x16x32_bf16(a0, wf[nt][0], c, 0, 0, 0);
            c = __builtin_amdgcn_mfma_f32_16x16x32_bf16(a1, wf[nt][1], c, 0, 0, 0);
            c = __builtin_amdgcn_mfma_f32_16x16x32_bf16(a2, wf[nt][2], c, 0, 0, 0);
            c = __builtin_amdgcn_mfma_f32_16x16x32_bf16(a3, wf[nt][3], c, 0, 0, 0);
#pragma unroll
            for (int i = 0; i < 4; ++i) {
                float v = fmaxf(c[i] + bl[nt], 0.0f);
                outb[(size_t)(n0 + crow + i) * 64 + nt * 16 + (lane & 15)] = f2bf(v);
            }
        }
    }
}

// ---------------- MFMA pre-transform layer 3: g = h @ W3l.T (K=64, N=32) ----------------
__global__ void __launch_bounds__(256)
mfma_pretrans3(const ushort* __restrict__ hb, const ushort* __restrict__ wfrag,
               ushort* __restrict__ gb, int ntiles) {
    int wave = threadIdx.x >> 6;
    int lane = threadIdx.x & 63;

    bf16x8 wf[2][2];
#pragma unroll
    for (int nt = 0; nt < 2; ++nt)
#pragma unroll
        for (int ks = 0; ks < 2; ++ks)
            wf[nt][ks] = *(const bf16x8*)(wfrag + (size_t)((nt * 2 + ks) * 64 + lane) * 8);

    int arow = lane & 15;
    int koff = (lane >> 4) * 8;
    int crow = (lane >> 4) * 4;
    int nwaves = gridDim.x * 4;

    for (int tile = blockIdx.x * 4 + wave; tile < ntiles; tile += nwaves) {
        int n0 = tile * 16;
        const ushort* hrow = hb + (size_t)(n0 + arow) * 64 + koff;
        bf16x8 a0 = *(const bf16x8*)(hrow);
        bf16x8 a1 = *(const bf16x8*)(hrow + 32);
#pragma unroll
        for (int nt = 0; nt < 2; ++nt) {
            f32x4 c = {0.f, 0.f, 0.f, 0.f};
            c = __builtin_amdgcn_mfma_f32_16x16x32_bf16(a0, wf[nt][0], c, 0, 0, 0);
            c = __builtin_amdgcn_mfma_f32_16x16x32_bf16(a1, wf[nt][1], c, 0, 0, 0);
#pragma unroll
            for (int i = 0; i < 4; ++i)
                gb[(size_t)(n0 + crow + i) * 32 + nt * 16 + (lane & 15)] = f2bf(c[i]);
        }
    }
}

// ---------------- MFMA layer 3 + head: out = relu(mean32 + b3 + h@W3r.T) . Wreg + breg ----------------
__global__ void __launch_bounds__(256)
mfma_t3(const ushort* __restrict__ hb, const ushort* __restrict__ mean32b,
        const ushort* __restrict__ wfrag, const float* __restrict__ b3,
        const float* __restrict__ Wreg, const float* __restrict__ breg,
        float* __restrict__ out, int ntiles) {
    int wave = threadIdx.x >> 6;
    int lane = threadIdx.x & 63;

    bf16x8 wf[2][2];
#pragma unroll
    for (int nt = 0; nt < 2; ++nt)
#pragma unroll
        for (int ks = 0; ks < 2; ++ks)
            wf[nt][ks] = *(const bf16x8*)(wfrag + (size_t)((nt * 2 + ks) * 64 + lane) * 8);

    float bl[2], wr[2];
#pragma unroll
    for (int nt = 0; nt < 2; ++nt) {
        bl[nt] = b3[nt * 16 + (lane & 15)];
        wr[nt] = Wreg[nt * 16 + (lane & 15)];
    }
    float br = breg[0];

    int arow = lane & 15;
    int koff = (lane >> 4) * 8;
    int crow = (lane >> 4) * 4;
    int nwaves = gridDim.x * 4;

    for (int tile = blockIdx.x * 4 + wave; tile < ntiles; tile += nwaves) {
        int n0 = tile * 16;
        const ushort* hrow = hb + (size_t)(n0 + arow) * 64 + koff;
        bf16x8 a0 = *(const bf16x8*)(hrow);
        bf16x8 a1 = *(const bf16x8*)(hrow + 32);
        float part0 = 0.f, part1 = 0.f, part2 = 0.f, part3 = 0.f;
#pragma unroll
        for (int nt = 0; nt < 2; ++nt) {
            f32x4 c = {0.f, 0.f, 0.f, 0.f};
            c = __builtin_amdgcn_mfma_f32_16x16x32_bf16(a0, wf[nt][0], c, 0, 0, 0);
            c = __builtin_amdgcn_mfma_f32_16x16x32_bf16(a1, wf[nt][1], c, 0, 0, 0);
#pragma unroll
            for (int i = 0; i < 4; ++i) {
                ushort mw = mean32b[(size_t)(n0 + crow + i) * 32 + nt * 16 + (lane & 15)];
                float m = __uint_as_float((uint)mw << 16);
                float v = fmaxf(c[i] + bl[nt] + m, 0.0f) * wr[nt];
                if (i == 0) part0 += v;
                else if (i == 1) part1 += v;
                else if (i == 2) part2 += v;
                else part3 += v;
            }
        }
        // reduce across the 16 lanes of each group (lane bits 0-3)
#pragma unroll
        for (int s = 1; s < 16; s <<= 1) {
            part0 += __shfl_xor(part0, s, 64);
            part1 += __shfl_xor(part1, s, 64);
            part2 += __shfl_xor(part2, s, 64);
            part3 += __shfl_xor(part3, s, 64);
        }
        if ((lane & 15) == 0) {
            float4 o;
            o.x = part0 + br; o.y = part1 + br; o.z = part2 + br; o.w = part3 + br;
            *(float4*)(out + n0 + crow) = o;
        }
    }
}

extern "C" void kernel_launch(void* const* d_in, const int* in_sizes, int n_in,
                              void* d_out, int out_size, void* d_ws, size_t ws_size,
                              hipStream_t stream) {
    const float* x    = (const float*)d_in[0];
    const int*   ei   = (const int*)d_in[1];
    const float* W1l  = (const float*)d_in[2];
    const float* b1   = (const float*)d_in[3];
    const float* W1r  = (const float*)d_in[4];
    const float* W2l  = (const float*)d_in[5];
    const float* b2   = (const float*)d_in[6];
    const float* W2r  = (const float*)d_in[7];
    const float* W3l  = (const float*)d_in[8];
    const float* b3   = (const float*)d_in[9];
    const float* W3r  = (const float*)d_in[10];
    const float* Wreg = (const float*)d_in[11];
    const float* breg = (const float*)d_in[12];

    const int* src = ei;
    const int* dst = ei + N_EDGES;

    char* p = (char*)d_ws;
    auto alloc = [&](size_t bytes) {
        char* r = p;
        p += (bytes + 255) & ~(size_t)255;
        return r;
    };
    int*    degcnt = (int*)alloc(N_NODES * sizeof(int));
    int*    rowptr = (int*)alloc((N_NODES + 1) * sizeof(int));
    int*    partial= (int*)alloc(N_NODES * sizeof(int));
    int*    sums   = (int*)alloc(512 * sizeof(int));
    int*    cursor = (int*)alloc(NB * sizeof(int));
    int*    col    = (int*)alloc((size_t)N_EDGES * sizeof(int));
    float*  invdeg = (float*)alloc(N_NODES * sizeof(float));
    ushort* wfrag  = (ushort*)alloc(20480 * sizeof(ushort));
    // shared slot: part (6.4MB) -> xb (12.8MB) -> gb (6.4MB); lifetimes don't overlap
    char*   slot   = (char*)alloc((size_t)N_NODES * 64 * sizeof(ushort));
    int*    part   = (int*)slot;
    ushort* xb     = (ushort*)slot;
    ushort* gb     = (ushort*)slot;
    ushort* meanb  = (ushort*)alloc((size_t)N_NODES * 64 * sizeof(ushort)); // also mean32b
    ushort* mean32b= meanb;
    ushort* hb     = (ushort*)alloc((size_t)N_NODES * 64 * sizeof(ushort));
    float*  out    = (float*)d_out;

    const int TB = 256;
    int edgeBlocks   = (N_EDGES + TB - 1) / TB;
    int nodeBlocks   = (N_NODES + TB - 1) / TB;
    int gatherBlocks = (N_NODES + 3) / 4;
    int castBlocks   = ((N_NODES * 64 / 4) + TB - 1) / TB;
    const int mfmaBlocks = 512;   // 2048 waves, ~3 tiles each

    // ---- weight-frag prep + CSR build ----
    prep_wfrag<<<80, 256, 0, stream>>>(W1l, W1r, W2l, W2r, W3l, W3r, wfrag);
    hipMemsetAsync(degcnt, 0, N_NODES * sizeof(int), stream);
    hist_kernel<<<edgeBlocks, TB, 0, stream>>>(dst, degcnt, N_EDGES);
    scan_chunk<<<nodeBlocks, 256, 0, stream>>>(degcnt, partial, sums, N_NODES);
    scan_sums<<<1, 512, 0, stream>>>(sums, nodeBlocks);
    finalize_rowptr<<<nodeBlocks, 256, 0, stream>>>(partial, sums, rowptr, N_NODES);
    invdeg_rowptr<<<nodeBlocks, TB, 0, stream>>>(rowptr, invdeg, N_NODES);
    init_cursor<<<(NB + TB - 1) / TB, TB, 0, stream>>>(rowptr, cursor, NB);
    partition_kernel<<<256, 256, 0, stream>>>(src, dst, cursor, part, N_EDGES);
    bucket_fill<<<NB, 256, 0, stream>>>(rowptr, part, col, N_NODES);
    cast_bf16<<<castBlocks, TB, 0, stream>>>(x, xb, N_NODES * 64 / 4);  // after bucket_fill: xb aliases part

    // ---- layer 1 ----
    gather_mean<<<gatherBlocks, 256, 0, stream>>>(xb, rowptr, col, invdeg, meanb, N_NODES);
    mfma_transform<<<mfmaBlocks, 256, 0, stream>>>(xb, meanb, wfrag + 0, b1, hb, NTILES);

    // ---- layer 2 ----
    gather_mean<<<gatherBlocks, 256, 0, stream>>>(hb, rowptr, col, invdeg, meanb, N_NODES);
    mfma_transform<<<mfmaBlocks, 256, 0, stream>>>(hb, meanb, wfrag + 8192, b2, hb, NTILES);

    // ---- layer 3: pre-transform, 32-wide gather, fused head ----
    mfma_pretrans3<<<mfmaBlocks, 256, 0, stream>>>(hb, wfrag + 16384, gb, NTILES);  // gb aliases xb (dead)
    gather_mean32<<<gatherBlocks, 256, 0, stream>>>(gb, rowptr, col, invdeg, mean32b, N_NODES);
    mfma_t3<<<mfmaBlocks, 256, 0, stream>>>(hb, mean32b, wfrag + 18432, b3, Wreg, breg, out, NTILES);
}

// Round 7
// 242.494 us; speedup vs baseline: 9.5911x; 1.2483x over previous
//
#include <hip/hip_runtime.h>
#include <math.h>

#define N_NODES 100000
#define N_EDGES 1600000
#define NB 782              // ceil(N_NODES / 128) buckets, bucket = dst >> 7
#define NTILES 6250         // N_NODES / 16 (exact)

typedef unsigned int uint;
typedef __attribute__((ext_vector_type(8))) short bf16x8;
typedef __attribute__((ext_vector_type(4))) float f32x4;

__device__ inline ushort f2bf(float f) {
    uint u = __float_as_uint(f);
    uint r = (u + 0x7fffu + ((u >> 16) & 1u)) >> 16;
    return (ushort)r;
}
__device__ inline uint pack2bf(float lo, float hi) {
    return (uint)f2bf(lo) | ((uint)f2bf(hi) << 16);
}

// ---------------- cast x -> bf16 ----------------
__global__ void cast_bf16(const float* __restrict__ in, ushort* __restrict__ out, int n4) {
    int i = blockIdx.x * blockDim.x + threadIdx.x;
    if (i < n4) {
        float4 v = ((const float4*)in)[i];
        uint2 o;
        o.x = pack2bf(v.x, v.y);
        o.y = pack2bf(v.z, v.w);
        ((uint2*)out)[i] = o;
    }
}

// ---------------- weight-fragment prep (one-shot, 20480 elems) ----------------
__global__ void prep_wfrag(const float* __restrict__ W1l, const float* __restrict__ W1r,
                           const float* __restrict__ W2l, const float* __restrict__ W2r,
                           const float* __restrict__ W3l, const float* __restrict__ W3r,
                           ushort* __restrict__ wf) {
    int idx = blockIdx.x * 256 + threadIdx.x;
    if (idx >= 20480) return;
    const float *Wl, *Wr;
    int base, KT;
    if (idx < 8192)       { base = 0;     Wl = W1l; Wr = W1r; KT = 128; }
    else if (idx < 16384) { base = 8192;  Wl = W2l; Wr = W2r; KT = 128; }
    else if (idx < 18432) { base = 16384; Wl = W3l; Wr = 0;   KT = 64; }
    else                  { base = 18432; Wl = W3r; Wr = 0;   KT = 64; }
    int r = idx - base;
    int f = r >> 9;
    int l = (r >> 3) & 63;
    int i = r & 7;
    int nks = KT >> 5;
    int nt = f / nks, ks = f - nt * nks;
    int k = ks * 32 + ((l >> 4) << 3) + i;
    int j = nt * 16 + (l & 15);
    float v = (k < 64) ? Wl[j * 64 + k] : Wr[j * 64 + (k - 64)];
    wf[idx] = f2bf(v);
}

// ---------------- bucket-level histogram (LDS pre-aggregation) ----------------
__global__ void bucket_hist(const int* __restrict__ dst, int* __restrict__ bucketCnt, int nE) {
    __shared__ int hist[NB];
    const int PER = (N_EDGES + 255) / 256;
    int e0 = blockIdx.x * PER;
    int e1 = min(e0 + PER, nE);
    for (int i = threadIdx.x; i < NB; i += 256) hist[i] = 0;
    __syncthreads();
    for (int e = e0 + threadIdx.x; e < e1; e += 256)
        atomicAdd(&hist[dst[e] >> 7], 1);
    __syncthreads();
    for (int i = threadIdx.x; i < NB; i += 256) {
        int c = hist[i];
        if (c) atomicAdd(&bucketCnt[i], c);
    }
}

// ---------------- scan bucket totals -> bucketBase + cursor ----------------
__global__ void scan_buckets(const int* __restrict__ bucketCnt, int* __restrict__ bucketBase,
                             int* __restrict__ cursor) {
    __shared__ int s[1024];
    int tid = threadIdx.x;
    int v = (tid < NB) ? bucketCnt[tid] : 0;
    s[tid] = v;
    __syncthreads();
    for (int off = 1; off < 1024; off <<= 1) {
        int t = (tid >= off) ? s[tid - off] : 0;
        __syncthreads();
        s[tid] += t;
        __syncthreads();
    }
    if (tid < NB) {
        int excl = s[tid] - v;
        bucketBase[tid] = excl;
        cursor[tid] = excl;
    }
    if (tid == 0) bucketBase[NB] = s[NB - 1];
}

// ---------------- partition edges into bucket regions ----------------
__global__ void partition_kernel(const int* __restrict__ src, const int* __restrict__ dst,
                                 int* __restrict__ cursor, int* __restrict__ part, int nE) {
    __shared__ int hist[NB];
    __shared__ int base[NB];
    __shared__ int rank[NB];
    const int PER = (N_EDGES + 255) / 256;
    int e0 = blockIdx.x * PER;
    int e1 = min(e0 + PER, nE);
    for (int i = threadIdx.x; i < NB; i += 256) { hist[i] = 0; rank[i] = 0; }
    __syncthreads();
    for (int e = e0 + threadIdx.x; e < e1; e += 256)
        atomicAdd(&hist[dst[e] >> 7], 1);
    __syncthreads();
    for (int i = threadIdx.x; i < NB; i += 256) {
        int c = hist[i];
        base[i] = c ? atomicAdd(&cursor[i], c) : 0;
    }
    __syncthreads();
    for (int e = e0 + threadIdx.x; e < e1; e += 256) {
        int d = dst[e];
        int bk = d >> 7;
        int r = atomicAdd(&rank[bk], 1);
        part[base[bk] + r] = src[e] | ((d & 127) << 20);
    }
}

// ---------------- bucket fill: per-dst counts, rowptr, invdeg, col scatter ----------------
__global__ void bucket_fill2(const int* __restrict__ bucketBase, const int* __restrict__ part,
                             int* __restrict__ col, int* __restrict__ rowptr,
                             float* __restrict__ invdeg, int n) {
    __shared__ int cnt[128];
    __shared__ int cnt2[128];
    __shared__ int exclS[128];
    __shared__ int s[128];
    int b = blockIdx.x;
    int d0 = b << 7;
    int dl = min(128, n - d0);
    int ebeg = bucketBase[b], eend = bucketBase[b + 1];
    if (threadIdx.x < 128) { cnt[threadIdx.x] = 0; cnt2[threadIdx.x] = 0; }
    __syncthreads();
    for (int i = ebeg + (int)threadIdx.x; i < eend; i += 256)
        atomicAdd(&cnt[part[i] >> 20], 1);
    __syncthreads();
    if (threadIdx.x < 128) s[threadIdx.x] = cnt[threadIdx.x];
    __syncthreads();
    for (int off = 1; off < 128; off <<= 1) {
        int t = 0;
        if (threadIdx.x < 128 && threadIdx.x >= (unsigned)off) t = s[threadIdx.x - off];
        __syncthreads();
        if (threadIdx.x < 128) s[threadIdx.x] += t;
        __syncthreads();
    }
    if ((int)threadIdx.x < dl) {
        int c = cnt[threadIdx.x];
        int ex = ebeg + s[threadIdx.x] - c;
        rowptr[d0 + threadIdx.x] = ex;
        invdeg[d0 + threadIdx.x] = 1.0f / fmaxf((float)c, 1.0f);
        exclS[threadIdx.x] = ex;
    }
    if (threadIdx.x == 0 && d0 + dl == n) rowptr[n] = eend;
    __syncthreads();
    for (int i = ebeg + (int)threadIdx.x; i < eend; i += 256) {
        int v = part[i];
        int doff = v >> 20;
        int pos = exclS[doff] + atomicAdd(&cnt2[doff], 1);
        col[pos] = v & 0xFFFFF;
    }
}

// ---------------- gather mean (64 bf16 features): wave per node, 4 edges per VMEM ----------------
__global__ void gather_mean(const ushort* __restrict__ xb, const int* __restrict__ rowptr,
                            const int* __restrict__ col, const float* __restrict__ invdeg,
                            ushort* __restrict__ meanb, int n) {
    int wave = threadIdx.x >> 6;
    int lane = threadIdx.x & 63;
    int node = blockIdx.x * 4 + wave;
    if (node >= n) return;
    int beg = rowptr[node];
    int end = rowptr[node + 1];
    int grp = lane >> 4;
    int fb = (lane & 15) * 4;
    float a0 = 0.0f, a1 = 0.0f, a2 = 0.0f, a3 = 0.0f;
    for (int i = beg; i < end; i += 64) {
        int idx = i + lane;
        int ci = (idx < end) ? col[idx] : 0;
        int cnt = min(64, end - i);
        int nq = (cnt + 3) >> 2;
#pragma unroll 4
        for (int t = 0; t < nq; ++t) {
            int e = t * 4 + grp;
            int s = __shfl(ci, e, 64);
            if (e < cnt) {
                uint2 w = *(const uint2*)(xb + (size_t)s * 64 + fb);
                a0 += __uint_as_float(w.x << 16);
                a1 += __uint_as_float(w.x & 0xffff0000u);
                a2 += __uint_as_float(w.y << 16);
                a3 += __uint_as_float(w.y & 0xffff0000u);
            }
        }
    }
    a0 += __shfl_xor(a0, 16, 64); a0 += __shfl_xor(a0, 32, 64);
    a1 += __shfl_xor(a1, 16, 64); a1 += __shfl_xor(a1, 32, 64);
    a2 += __shfl_xor(a2, 16, 64); a2 += __shfl_xor(a2, 32, 64);
    a3 += __shfl_xor(a3, 16, 64); a3 += __shfl_xor(a3, 32, 64);
    if (grp == 0) {
        float id = invdeg[node];
        uint2 o;
        o.x = pack2bf(a0 * id, a1 * id);
        o.y = pack2bf(a2 * id, a3 * id);
        *(uint2*)(meanb + (size_t)node * 64 + fb) = o;
    }
}

// ---------------- gather mean (32 bf16 features, pre-transformed layer 3) ----------------
__global__ void gather_mean32(const ushort* __restrict__ gb, const int* __restrict__ rowptr,
                              const int* __restrict__ col, const float* __restrict__ invdeg,
                              ushort* __restrict__ mean32b, int n) {
    int wave = threadIdx.x >> 6;
    int lane = threadIdx.x & 63;
    int node = blockIdx.x * 4 + wave;
    if (node >= n) return;
    int beg = rowptr[node];
    int end = rowptr[node + 1];
    int grp = lane >> 4;
    int fb = (lane & 15) * 2;
    float a0 = 0.0f, a1 = 0.0f;
    for (int i = beg; i < end; i += 64) {
        int idx = i + lane;
        int ci = (idx < end) ? col[idx] : 0;
        int cnt = min(64, end - i);
        int nq = (cnt + 3) >> 2;
#pragma unroll 4
        for (int t = 0; t < nq; ++t) {
            int e = t * 4 + grp;
            int s = __shfl(ci, e, 64);
            if (e < cnt) {
                uint w = *(const uint*)(gb + (size_t)s * 32 + fb);
                a0 += __uint_as_float(w << 16);
                a1 += __uint_as_float(w & 0xffff0000u);
            }
        }
    }
    a0 += __shfl_xor(a0, 16, 64); a0 += __shfl_xor(a0, 32, 64);
    a1 += __shfl_xor(a1, 16, 64); a1 += __shfl_xor(a1, 32, 64);
    if (grp == 0) {
        float id = invdeg[node];
        *(uint*)(mean32b + (size_t)node * 32 + fb) = pack2bf(a0 * id, a1 * id);
    }
}

// ---------------- MFMA transform (layers 1,2): h = relu([mean|x] @ Wcomb + b) ----------------
__global__ void __launch_bounds__(256)
mfma_transform(const ushort* __restrict__ rootb, const ushort* __restrict__ meanb,
               const ushort* __restrict__ wfrag, const float* __restrict__ bias,
               ushort* __restrict__ outb, int ntiles) {
    int wave = threadIdx.x >> 6;
    int lane = threadIdx.x & 63;

    bf16x8 wf[4][4];
#pragma unroll
    for (int nt = 0; nt < 4; ++nt)
#pragma unroll
        for (int ks = 0; ks < 4; ++ks)
            wf[nt][ks] = *(const bf16x8*)(wfrag + (size_t)((nt * 4 + ks) * 64 + lane) * 8);

    float bl[4];
#pragma unroll
    for (int nt = 0; nt < 4; ++nt) bl[nt] = bias[nt * 16 + (lane & 15)];

    int arow = lane & 15;
    int koff = (lane >> 4) * 8;
    int crow = (lane >> 4) * 4;
    int nwaves = gridDim.x * 4;

    for (int tile = blockIdx.x * 4 + wave; tile < ntiles; tile += nwaves) {
        int n0 = tile * 16;
        const ushort* mrow = meanb + (size_t)(n0 + arow) * 64 + koff;
        const ushort* xrow = rootb + (size_t)(n0 + arow) * 64 + koff;
        bf16x8 a0 = *(const bf16x8*)(mrow);
        bf16x8 a1 = *(const bf16x8*)(mrow + 32);
        bf16x8 a2 = *(const bf16x8*)(xrow);
        bf16x8 a3 = *(const bf16x8*)(xrow + 32);
#pragma unroll
        for (int nt = 0; nt < 4; ++nt) {
            f32x4 c = {0.f, 0.f, 0.f, 0.f};
            c = __builtin_amdgcn_mfma_f32_16x16x32_bf16(a0, wf[nt][0], c, 0, 0, 0);
            c = __builtin_amdgcn_mfma_f32_16x16x32_bf16(a1, wf[nt][1], c, 0, 0, 0);
            c = __builtin_amdgcn_mfma_f32_16x16x32_bf16(a2, wf[nt][2], c, 0, 0, 0);
            c = __builtin_amdgcn_mfma_f32_16x16x32_bf16(a3, wf[nt][3], c, 0, 0, 0);
#pragma unroll
            for (int i = 0; i < 4; ++i) {
                float v = fmaxf(c[i] + bl[nt], 0.0f);
                outb[(size_t)(n0 + crow + i) * 64 + nt * 16 + (lane & 15)] = f2bf(v);
            }
        }
    }
}

// ---------------- MFMA pre-transform layer 3: g = h @ W3l.T (K=64, N=32) ----------------
__global__ void __launch_bounds__(256)
mfma_pretrans3(const ushort* __restrict__ hb, const ushort* __restrict__ wfrag,
               ushort* __restrict__ gb, int ntiles) {
    int wave = threadIdx.x >> 6;
    int lane = threadIdx.x & 63;

    bf16x8 wf[2][2];
#pragma unroll
    for (int nt = 0; nt < 2; ++nt)
#pragma unroll
        for (int ks = 0; ks < 2; ++ks)
            wf[nt][ks] = *(const bf16x8*)(wfrag + (size_t)((nt * 2 + ks) * 64 + lane) * 8);

    int arow = lane & 15;
    int koff = (lane >> 4) * 8;
    int crow = (lane >> 4) * 4;
    int nwaves = gridDim.x * 4;

    for (int tile = blockIdx.x * 4 + wave; tile < ntiles; tile += nwaves) {
        int n0 = tile * 16;
        const ushort* hrow = hb + (size_t)(n0 + arow) * 64 + koff;
        bf16x8 a0 = *(const bf16x8*)(hrow);
        bf16x8 a1 = *(const bf16x8*)(hrow + 32);
#pragma unroll
        for (int nt = 0; nt < 2; ++nt) {
            f32x4 c = {0.f, 0.f, 0.f, 0.f};
            c = __builtin_amdgcn_mfma_f32_16x16x32_bf16(a0, wf[nt][0], c, 0, 0, 0);
            c = __builtin_amdgcn_mfma_f32_16x16x32_bf16(a1, wf[nt][1], c, 0, 0, 0);
#pragma unroll
            for (int i = 0; i < 4; ++i)
                gb[(size_t)(n0 + crow + i) * 32 + nt * 16 + (lane & 15)] = f2bf(c[i]);
        }
    }
}

// ---------------- MFMA layer 3 + head ----------------
__global__ void __launch_bounds__(256)
mfma_t3(const ushort* __restrict__ hb, const ushort* __restrict__ mean32b,
        const ushort* __restrict__ wfrag, const float* __restrict__ b3,
        const float* __restrict__ Wreg, const float* __restrict__ breg,
        float* __restrict__ out, int ntiles) {
    int wave = threadIdx.x >> 6;
    int lane = threadIdx.x & 63;

    bf16x8 wf[2][2];
#pragma unroll
    for (int nt = 0; nt < 2; ++nt)
#pragma unroll
        for (int ks = 0; ks < 2; ++ks)
            wf[nt][ks] = *(const bf16x8*)(wfrag + (size_t)((nt * 2 + ks) * 64 + lane) * 8);

    float bl[2], wr[2];
#pragma unroll
    for (int nt = 0; nt < 2; ++nt) {
        bl[nt] = b3[nt * 16 + (lane & 15)];
        wr[nt] = Wreg[nt * 16 + (lane & 15)];
    }
    float br = breg[0];

    int arow = lane & 15;
    int koff = (lane >> 4) * 8;
    int crow = (lane >> 4) * 4;
    int nwaves = gridDim.x * 4;

    for (int tile = blockIdx.x * 4 + wave; tile < ntiles; tile += nwaves) {
        int n0 = tile * 16;
        const ushort* hrow = hb + (size_t)(n0 + arow) * 64 + koff;
        bf16x8 a0 = *(const bf16x8*)(hrow);
        bf16x8 a1 = *(const bf16x8*)(hrow + 32);
        float part0 = 0.f, part1 = 0.f, part2 = 0.f, part3 = 0.f;
#pragma unroll
        for (int nt = 0; nt < 2; ++nt) {
            f32x4 c = {0.f, 0.f, 0.f, 0.f};
            c = __builtin_amdgcn_mfma_f32_16x16x32_bf16(a0, wf[nt][0], c, 0, 0, 0);
            c = __builtin_amdgcn_mfma_f32_16x16x32_bf16(a1, wf[nt][1], c, 0, 0, 0);
#pragma unroll
            for (int i = 0; i < 4; ++i) {
                ushort mw = mean32b[(size_t)(n0 + crow + i) * 32 + nt * 16 + (lane & 15)];
                float m = __uint_as_float((uint)mw << 16);
                float v = fmaxf(c[i] + bl[nt] + m, 0.0f) * wr[nt];
                if (i == 0) part0 += v;
                else if (i == 1) part1 += v;
                else if (i == 2) part2 += v;
                else part3 += v;
            }
        }
#pragma unroll
        for (int s = 1; s < 16; s <<= 1) {
            part0 += __shfl_xor(part0, s, 64);
            part1 += __shfl_xor(part1, s, 64);
            part2 += __shfl_xor(part2, s, 64);
            part3 += __shfl_xor(part3, s, 64);
        }
        if ((lane & 15) == 0) {
            float4 o;
            o.x = part0 + br; o.y = part1 + br; o.z = part2 + br; o.w = part3 + br;
            *(float4*)(out + n0 + crow) = o;
        }
    }
}

extern "C" void kernel_launch(void* const* d_in, const int* in_sizes, int n_in,
                              void* d_out, int out_size, void* d_ws, size_t ws_size,
                              hipStream_t stream) {
    const float* x    = (const float*)d_in[0];
    const int*   ei   = (const int*)d_in[1];
    const float* W1l  = (const float*)d_in[2];
    const float* b1   = (const float*)d_in[3];
    const float* W1r  = (const float*)d_in[4];
    const float* W2l  = (const float*)d_in[5];
    const float* b2   = (const float*)d_in[6];
    const float* W2r  = (const float*)d_in[7];
    const float* W3l  = (const float*)d_in[8];
    const float* b3   = (const float*)d_in[9];
    const float* W3r  = (const float*)d_in[10];
    const float* Wreg = (const float*)d_in[11];
    const float* breg = (const float*)d_in[12];

    const int* src = ei;
    const int* dst = ei + N_EDGES;

    char* p = (char*)d_ws;
    auto alloc = [&](size_t bytes) {
        char* r = p;
        p += (bytes + 255) & ~(size_t)255;
        return r;
    };
    int*    bucketCnt = (int*)alloc(NB * sizeof(int));
    int*    bucketBase= (int*)alloc((NB + 1) * sizeof(int));
    int*    cursor    = (int*)alloc(NB * sizeof(int));
    int*    rowptr    = (int*)alloc((N_NODES + 1) * sizeof(int));
    int*    col       = (int*)alloc((size_t)N_EDGES * sizeof(int));
    float*  invdeg    = (float*)alloc(N_NODES * sizeof(float));
    ushort* wfrag     = (ushort*)alloc(20480 * sizeof(ushort));
    // shared slot: part (6.4MB) -> xb (12.8MB) -> gb (6.4MB); lifetimes don't overlap
    char*   slot   = (char*)alloc((size_t)N_NODES * 64 * sizeof(ushort));
    int*    part   = (int*)slot;
    ushort* xb     = (ushort*)slot;
    ushort* gb     = (ushort*)slot;
    ushort* meanb  = (ushort*)alloc((size_t)N_NODES * 64 * sizeof(ushort)); // also mean32b
    ushort* mean32b= meanb;
    ushort* hb     = (ushort*)alloc((size_t)N_NODES * 64 * sizeof(ushort));
    float*  out    = (float*)d_out;

    const int TB = 256;
    int gatherBlocks = (N_NODES + 3) / 4;
    int castBlocks   = ((N_NODES * 64 / 4) + TB - 1) / TB;
    const int mfmaBlocks = 512;

    // ---- weight-frag prep + CSR build ----
    prep_wfrag<<<80, 256, 0, stream>>>(W1l, W1r, W2l, W2r, W3l, W3r, wfrag);
    hipMemsetAsync(bucketCnt, 0, NB * sizeof(int), stream);
    bucket_hist<<<256, 256, 0, stream>>>(dst, bucketCnt, N_EDGES);
    scan_buckets<<<1, 1024, 0, stream>>>(bucketCnt, bucketBase, cursor);
    partition_kernel<<<256, 256, 0, stream>>>(src, dst, cursor, part, N_EDGES);
    bucket_fill2<<<NB, 256, 0, stream>>>(bucketBase, part, col, rowptr, invdeg, N_NODES);
    cast_bf16<<<castBlocks, TB, 0, stream>>>(x, xb, N_NODES * 64 / 4);  // after bucket_fill2: xb aliases part

    // ---- layer 1 ----
    gather_mean<<<gatherBlocks, 256, 0, stream>>>(xb, rowptr, col, invdeg, meanb, N_NODES);
    mfma_transform<<<mfmaBlocks, 256, 0, stream>>>(xb, meanb, wfrag + 0, b1, hb, NTILES);

    // ---- layer 2 ----
    gather_mean<<<gatherBlocks, 256, 0, stream>>>(hb, rowptr, col, invdeg, meanb, N_NODES);
    mfma_transform<<<mfmaBlocks, 256, 0, stream>>>(hb, meanb, wfrag + 8192, b2, hb, NTILES);

    // ---- layer 3: pre-transform, 32-wide gather, fused head ----
    mfma_pretrans3<<<mfmaBlocks, 256, 0, stream>>>(hb, wfrag + 16384, gb, NTILES);  // gb aliases xb (dead)
    gather_mean32<<<gatherBlocks, 256, 0, stream>>>(gb, rowptr, col, invdeg, mean32b, N_NODES);
    mfma_t3<<<mfmaBlocks, 256, 0, stream>>>(hb, mean32b, wfrag + 18432, b3, Wreg, breg, out, NTILES);
}

// Round 8
// 194.238 us; speedup vs baseline: 11.9739x; 1.2484x over previous
//
#include <hip/hip_runtime.h>
#include <math.h>

#define N_NODES 100000
#define N_EDGES 1600000
#define NB 782              // ceil(N_NODES / 128) buckets, bucket = dst >> 7
#define NTILES 6250         // N_NODES / 16 (exact)

typedef unsigned int uint;
typedef __attribute__((ext_vector_type(8))) short bf16x8;
typedef __attribute__((ext_vector_type(4))) float f32x4;

__device__ inline ushort f2bf(float f) {
    uint u = __float_as_uint(f);
    uint r = (u + 0x7fffu + ((u >> 16) & 1u)) >> 16;
    return (ushort)r;
}
__device__ inline uint pack2bf(float lo, float hi) {
    return (uint)f2bf(lo) | ((uint)f2bf(hi) << 16);
}

// ---------------- cast x -> bf16 ----------------
__global__ void cast_bf16(const float* __restrict__ in, ushort* __restrict__ out, int n4) {
    int i = blockIdx.x * blockDim.x + threadIdx.x;
    if (i < n4) {
        float4 v = ((const float4*)in)[i];
        uint2 o;
        o.x = pack2bf(v.x, v.y);
        o.y = pack2bf(v.z, v.w);
        ((uint2*)out)[i] = o;
    }
}

// ---------------- weight-fragment prep (one-shot, 20480 elems) ----------------
__global__ void prep_wfrag(const float* __restrict__ W1l, const float* __restrict__ W1r,
                           const float* __restrict__ W2l, const float* __restrict__ W2r,
                           const float* __restrict__ W3l, const float* __restrict__ W3r,
                           ushort* __restrict__ wf) {
    int idx = blockIdx.x * 256 + threadIdx.x;
    if (idx >= 20480) return;
    const float *Wl, *Wr;
    int base, KT;
    if (idx < 8192)       { base = 0;     Wl = W1l; Wr = W1r; KT = 128; }
    else if (idx < 16384) { base = 8192;  Wl = W2l; Wr = W2r; KT = 128; }
    else if (idx < 18432) { base = 16384; Wl = W3l; Wr = 0;   KT = 64; }
    else                  { base = 18432; Wl = W3r; Wr = 0;   KT = 64; }
    int r = idx - base;
    int f = r >> 9;
    int l = (r >> 3) & 63;
    int i = r & 7;
    int nks = KT >> 5;
    int nt = f / nks, ks = f - nt * nks;
    int k = ks * 32 + ((l >> 4) << 3) + i;
    int j = nt * 16 + (l & 15);
    float v = (k < 64) ? Wl[j * 64 + k] : Wr[j * 64 + (k - 64)];
    wf[idx] = f2bf(v);
}

// ---------------- bucket-level histogram (LDS pre-aggregation) ----------------
__global__ void bucket_hist(const int* __restrict__ dst, int* __restrict__ bucketCnt, int nE) {
    __shared__ int hist[NB];
    const int PER = (N_EDGES + 255) / 256;
    int e0 = blockIdx.x * PER;
    int e1 = min(e0 + PER, nE);
    for (int i = threadIdx.x; i < NB; i += 256) hist[i] = 0;
    __syncthreads();
    for (int e = e0 + threadIdx.x; e < e1; e += 256)
        atomicAdd(&hist[dst[e] >> 7], 1);
    __syncthreads();
    for (int i = threadIdx.x; i < NB; i += 256) {
        int c = hist[i];
        if (c) atomicAdd(&bucketCnt[i], c);
    }
}

// ---------------- scan bucket totals -> bucketBase + cursor ----------------
__global__ void scan_buckets(const int* __restrict__ bucketCnt, int* __restrict__ bucketBase,
                             int* __restrict__ cursor) {
    __shared__ int s[1024];
    int tid = threadIdx.x;
    int v = (tid < NB) ? bucketCnt[tid] : 0;
    s[tid] = v;
    __syncthreads();
    for (int off = 1; off < 1024; off <<= 1) {
        int t = (tid >= off) ? s[tid - off] : 0;
        __syncthreads();
        s[tid] += t;
        __syncthreads();
    }
    if (tid < NB) {
        int excl = s[tid] - v;
        bucketBase[tid] = excl;
        cursor[tid] = excl;
    }
    if (tid == 0) bucketBase[NB] = s[NB - 1];
}

// ---------------- partition edges into bucket regions ----------------
__global__ void partition_kernel(const int* __restrict__ src, const int* __restrict__ dst,
                                 int* __restrict__ cursor, int* __restrict__ part, int nE) {
    __shared__ int hist[NB];
    __shared__ int base[NB];
    __shared__ int rank[NB];
    const int PER = (N_EDGES + 255) / 256;
    int e0 = blockIdx.x * PER;
    int e1 = min(e0 + PER, nE);
    for (int i = threadIdx.x; i < NB; i += 256) { hist[i] = 0; rank[i] = 0; }
    __syncthreads();
    for (int e = e0 + threadIdx.x; e < e1; e += 256)
        atomicAdd(&hist[dst[e] >> 7], 1);
    __syncthreads();
    for (int i = threadIdx.x; i < NB; i += 256) {
        int c = hist[i];
        base[i] = c ? atomicAdd(&cursor[i], c) : 0;
    }
    __syncthreads();
    for (int e = e0 + threadIdx.x; e < e1; e += 256) {
        int d = dst[e];
        int bk = d >> 7;
        int r = atomicAdd(&rank[bk], 1);
        part[base[bk] + r] = src[e] | ((d & 127) << 20);
    }
}

// ---------------- bucket fill: per-dst counts, rowptr, invdeg, col scatter ----------------
__global__ void bucket_fill2(const int* __restrict__ bucketBase, const int* __restrict__ part,
                             int* __restrict__ col, int* __restrict__ rowptr,
                             float* __restrict__ invdeg, int n) {
    __shared__ int cnt[128];
    __shared__ int cnt2[128];
    __shared__ int exclS[128];
    __shared__ int s[128];
    int b = blockIdx.x;
    int d0 = b << 7;
    int dl = min(128, n - d0);
    int ebeg = bucketBase[b], eend = bucketBase[b + 1];
    if (threadIdx.x < 128) { cnt[threadIdx.x] = 0; cnt2[threadIdx.x] = 0; }
    __syncthreads();
    for (int i = ebeg + (int)threadIdx.x; i < eend; i += 256)
        atomicAdd(&cnt[part[i] >> 20], 1);
    __syncthreads();
    if (threadIdx.x < 128) s[threadIdx.x] = cnt[threadIdx.x];
    __syncthreads();
    for (int off = 1; off < 128; off <<= 1) {
        int t = 0;
        if (threadIdx.x < 128 && threadIdx.x >= (unsigned)off) t = s[threadIdx.x - off];
        __syncthreads();
        if (threadIdx.x < 128) s[threadIdx.x] += t;
        __syncthreads();
    }
    if ((int)threadIdx.x < dl) {
        int c = cnt[threadIdx.x];
        int ex = ebeg + s[threadIdx.x] - c;
        rowptr[d0 + threadIdx.x] = ex;
        invdeg[d0 + threadIdx.x] = 1.0f / fmaxf((float)c, 1.0f);
        exclS[threadIdx.x] = ex;
    }
    if (threadIdx.x == 0 && d0 + dl == n) rowptr[n] = eend;
    __syncthreads();
    for (int i = ebeg + (int)threadIdx.x; i < eend; i += 256) {
        int v = part[i];
        int doff = v >> 20;
        int pos = exclS[doff] + atomicAdd(&cnt2[doff], 1);
        col[pos] = v & 0xFFFFF;
    }
}

// ---------------- gather mean (64 bf16 feats): 8-lane group per node, 16B/lane ----------------
// 8 nodes per wave, 8 independent chains, 8 edges (1KB) per VMEM instruction, no reduce.
__global__ void gather_mean(const ushort* __restrict__ xb, const int* __restrict__ rowptr,
                            const int* __restrict__ col, const float* __restrict__ invdeg,
                            ushort* __restrict__ meanb, int n) {
    int tid = blockIdx.x * blockDim.x + threadIdx.x;
    int wid = tid >> 6;
    int lane = threadIdx.x & 63;
    int grp = lane >> 3;      // 0..7: node within wave
    int li = lane & 7;        // lane in group: feature slice
    int node = wid * 8 + grp;
    if (node >= n) return;
    int beg = rowptr[node];
    int end = rowptr[node + 1];
    int fb = li * 8;
    float a0 = 0.f, a1 = 0.f, a2 = 0.f, a3 = 0.f, a4 = 0.f, a5 = 0.f, a6 = 0.f, a7 = 0.f;
    for (int i = beg; i < end; i += 8) {
        int idx = i + li;
        int ci = (idx < end) ? col[idx] : 0;
        int cnt = end - i;
#pragma unroll
        for (int t = 0; t < 8; ++t) {
            if (t < cnt) {
                int s = __shfl(ci, grp * 8 + t, 64);
                uint4 w = *(const uint4*)(xb + (size_t)s * 64 + fb);
                a0 += __uint_as_float(w.x << 16);
                a1 += __uint_as_float(w.x & 0xffff0000u);
                a2 += __uint_as_float(w.y << 16);
                a3 += __uint_as_float(w.y & 0xffff0000u);
                a4 += __uint_as_float(w.z << 16);
                a5 += __uint_as_float(w.z & 0xffff0000u);
                a6 += __uint_as_float(w.w << 16);
                a7 += __uint_as_float(w.w & 0xffff0000u);
            }
        }
    }
    float id = invdeg[node];
    uint4 o;
    o.x = pack2bf(a0 * id, a1 * id);
    o.y = pack2bf(a2 * id, a3 * id);
    o.z = pack2bf(a4 * id, a5 * id);
    o.w = pack2bf(a6 * id, a7 * id);
    *(uint4*)(meanb + (size_t)node * 64 + fb) = o;
}

// ---------------- gather mean (32 bf16 feats): 4-lane group per node, 16B/lane ----------------
__global__ void gather_mean32(const ushort* __restrict__ gb, const int* __restrict__ rowptr,
                              const int* __restrict__ col, const float* __restrict__ invdeg,
                              ushort* __restrict__ mean32b, int n) {
    int tid = blockIdx.x * blockDim.x + threadIdx.x;
    int wid = tid >> 6;
    int lane = threadIdx.x & 63;
    int grp = lane >> 2;      // 0..15: node within wave
    int li = lane & 3;        // feature slice
    int node = wid * 16 + grp;
    if (node >= n) return;
    int beg = rowptr[node];
    int end = rowptr[node + 1];
    int fb = li * 8;
    float a0 = 0.f, a1 = 0.f, a2 = 0.f, a3 = 0.f, a4 = 0.f, a5 = 0.f, a6 = 0.f, a7 = 0.f;
    for (int i = beg; i < end; i += 4) {
        int idx = i + li;
        int ci = (idx < end) ? col[idx] : 0;
        int cnt = end - i;
#pragma unroll
        for (int t = 0; t < 4; ++t) {
            if (t < cnt) {
                int s = __shfl(ci, grp * 4 + t, 64);
                uint4 w = *(const uint4*)(gb + (size_t)s * 32 + fb);
                a0 += __uint_as_float(w.x << 16);
                a1 += __uint_as_float(w.x & 0xffff0000u);
                a2 += __uint_as_float(w.y << 16);
                a3 += __uint_as_float(w.y & 0xffff0000u);
                a4 += __uint_as_float(w.z << 16);
                a5 += __uint_as_float(w.z & 0xffff0000u);
                a6 += __uint_as_float(w.w << 16);
                a7 += __uint_as_float(w.w & 0xffff0000u);
            }
        }
    }
    float id = invdeg[node];
    uint4 o;
    o.x = pack2bf(a0 * id, a1 * id);
    o.y = pack2bf(a2 * id, a3 * id);
    o.z = pack2bf(a4 * id, a5 * id);
    o.w = pack2bf(a6 * id, a7 * id);
    *(uint4*)(mean32b + (size_t)node * 32 + fb) = o;
}

// ---------------- MFMA transform (layers 1,2): h = relu([mean|x] @ Wcomb + b) ----------------
__global__ void __launch_bounds__(256)
mfma_transform(const ushort* __restrict__ rootb, const ushort* __restrict__ meanb,
               const ushort* __restrict__ wfrag, const float* __restrict__ bias,
               ushort* __restrict__ outb, int ntiles) {
    int wave = threadIdx.x >> 6;
    int lane = threadIdx.x & 63;

    bf16x8 wf[4][4];
#pragma unroll
    for (int nt = 0; nt < 4; ++nt)
#pragma unroll
        for (int ks = 0; ks < 4; ++ks)
            wf[nt][ks] = *(const bf16x8*)(wfrag + (size_t)((nt * 4 + ks) * 64 + lane) * 8);

    float bl[4];
#pragma unroll
    for (int nt = 0; nt < 4; ++nt) bl[nt] = bias[nt * 16 + (lane & 15)];

    int arow = lane & 15;
    int koff = (lane >> 4) * 8;
    int crow = (lane >> 4) * 4;
    int nwaves = gridDim.x * 4;

    for (int tile = blockIdx.x * 4 + wave; tile < ntiles; tile += nwaves) {
        int n0 = tile * 16;
        const ushort* mrow = meanb + (size_t)(n0 + arow) * 64 + koff;
        const ushort* xrow = rootb + (size_t)(n0 + arow) * 64 + koff;
        bf16x8 a0 = *(const bf16x8*)(mrow);
        bf16x8 a1 = *(const bf16x8*)(mrow + 32);
        bf16x8 a2 = *(const bf16x8*)(xrow);
        bf16x8 a3 = *(const bf16x8*)(xrow + 32);
#pragma unroll
        for (int nt = 0; nt < 4; ++nt) {
            f32x4 c = {0.f, 0.f, 0.f, 0.f};
            c = __builtin_amdgcn_mfma_f32_16x16x32_bf16(a0, wf[nt][0], c, 0, 0, 0);
            c = __builtin_amdgcn_mfma_f32_16x16x32_bf16(a1, wf[nt][1], c, 0, 0, 0);
            c = __builtin_amdgcn_mfma_f32_16x16x32_bf16(a2, wf[nt][2], c, 0, 0, 0);
            c = __builtin_amdgcn_mfma_f32_16x16x32_bf16(a3, wf[nt][3], c, 0, 0, 0);
#pragma unroll
            for (int i = 0; i < 4; ++i) {
                float v = fmaxf(c[i] + bl[nt], 0.0f);
                outb[(size_t)(n0 + crow + i) * 64 + nt * 16 + (lane & 15)] = f2bf(v);
            }
        }
    }
}

// ---------------- MFMA pre-transform layer 3: g = h @ W3l.T (K=64, N=32) ----------------
__global__ void __launch_bounds__(256)
mfma_pretrans3(const ushort* __restrict__ hb, const ushort* __restrict__ wfrag,
               ushort* __restrict__ gb, int ntiles) {
    int wave = threadIdx.x >> 6;
    int lane = threadIdx.x & 63;

    bf16x8 wf[2][2];
#pragma unroll
    for (int nt = 0; nt < 2; ++nt)
#pragma unroll
        for (int ks = 0; ks < 2; ++ks)
            wf[nt][ks] = *(const bf16x8*)(wfrag + (size_t)((nt * 2 + ks) * 64 + lane) * 8);

    int arow = lane & 15;
    int koff = (lane >> 4) * 8;
    int crow = (lane >> 4) * 4;
    int nwaves = gridDim.x * 4;

    for (int tile = blockIdx.x * 4 + wave; tile < ntiles; tile += nwaves) {
        int n0 = tile * 16;
        const ushort* hrow = hb + (size_t)(n0 + arow) * 64 + koff;
        bf16x8 a0 = *(const bf16x8*)(hrow);
        bf16x8 a1 = *(const bf16x8*)(hrow + 32);
#pragma unroll
        for (int nt = 0; nt < 2; ++nt) {
            f32x4 c = {0.f, 0.f, 0.f, 0.f};
            c = __builtin_amdgcn_mfma_f32_16x16x32_bf16(a0, wf[nt][0], c, 0, 0, 0);
            c = __builtin_amdgcn_mfma_f32_16x16x32_bf16(a1, wf[nt][1], c, 0, 0, 0);
#pragma unroll
            for (int i = 0; i < 4; ++i)
                gb[(size_t)(n0 + crow + i) * 32 + nt * 16 + (lane & 15)] = f2bf(c[i]);
        }
    }
}

// ---------------- MFMA layer 3 + head ----------------
__global__ void __launch_bounds__(256)
mfma_t3(const ushort* __restrict__ hb, const ushort* __restrict__ mean32b,
        const ushort* __restrict__ wfrag, const float* __restrict__ b3,
        const float* __restrict__ Wreg, const float* __restrict__ breg,
        float* __restrict__ out, int ntiles) {
    int wave = threadIdx.x >> 6;
    int lane = threadIdx.x & 63;

    bf16x8 wf[2][2];
#pragma unroll
    for (int nt = 0; nt < 2; ++nt)
#pragma unroll
        for (int ks = 0; ks < 2; ++ks)
            wf[nt][ks] = *(const bf16x8*)(wfrag + (size_t)((nt * 2 + ks) * 64 + lane) * 8);

    float bl[2], wr[2];
#pragma unroll
    for (int nt = 0; nt < 2; ++nt) {
        bl[nt] = b3[nt * 16 + (lane & 15)];
        wr[nt] = Wreg[nt * 16 + (lane & 15)];
    }
    float br = breg[0];

    int arow = lane & 15;
    int koff = (lane >> 4) * 8;
    int crow = (lane >> 4) * 4;
    int nwaves = gridDim.x * 4;

    for (int tile = blockIdx.x * 4 + wave; tile < ntiles; tile += nwaves) {
        int n0 = tile * 16;
        const ushort* hrow = hb + (size_t)(n0 + arow) * 64 + koff;
        bf16x8 a0 = *(const bf16x8*)(hrow);
        bf16x8 a1 = *(const bf16x8*)(hrow + 32);
        float part0 = 0.f, part1 = 0.f, part2 = 0.f, part3 = 0.f;
#pragma unroll
        for (int nt = 0; nt < 2; ++nt) {
            f32x4 c = {0.f, 0.f, 0.f, 0.f};
            c = __builtin_amdgcn_mfma_f32_16x16x32_bf16(a0, wf[nt][0], c, 0, 0, 0);
            c = __builtin_amdgcn_mfma_f32_16x16x32_bf16(a1, wf[nt][1], c, 0, 0, 0);
#pragma unroll
            for (int i = 0; i < 4; ++i) {
                ushort mw = mean32b[(size_t)(n0 + crow + i) * 32 + nt * 16 + (lane & 15)];
                float m = __uint_as_float((uint)mw << 16);
                float v = fmaxf(c[i] + bl[nt] + m, 0.0f) * wr[nt];
                if (i == 0) part0 += v;
                else if (i == 1) part1 += v;
                else if (i == 2) part2 += v;
                else part3 += v;
            }
        }
#pragma unroll
        for (int s = 1; s < 16; s <<= 1) {
            part0 += __shfl_xor(part0, s, 64);
            part1 += __shfl_xor(part1, s, 64);
            part2 += __shfl_xor(part2, s, 64);
            part3 += __shfl_xor(part3, s, 64);
        }
        if ((lane & 15) == 0) {
            float4 o;
            o.x = part0 + br; o.y = part1 + br; o.z = part2 + br; o.w = part3 + br;
            *(float4*)(out + n0 + crow) = o;
        }
    }
}

extern "C" void kernel_launch(void* const* d_in, const int* in_sizes, int n_in,
                              void* d_out, int out_size, void* d_ws, size_t ws_size,
                              hipStream_t stream) {
    const float* x    = (const float*)d_in[0];
    const int*   ei   = (const int*)d_in[1];
    const float* W1l  = (const float*)d_in[2];
    const float* b1   = (const float*)d_in[3];
    const float* W1r  = (const float*)d_in[4];
    const float* W2l  = (const float*)d_in[5];
    const float* b2   = (const float*)d_in[6];
    const float* W2r  = (const float*)d_in[7];
    const float* W3l  = (const float*)d_in[8];
    const float* b3   = (const float*)d_in[9];
    const float* W3r  = (const float*)d_in[10];
    const float* Wreg = (const float*)d_in[11];
    const float* breg = (const float*)d_in[12];

    const int* src = ei;
    const int* dst = ei + N_EDGES;

    char* p = (char*)d_ws;
    auto alloc = [&](size_t bytes) {
        char* r = p;
        p += (bytes + 255) & ~(size_t)255;
        return r;
    };
    int*    bucketCnt = (int*)alloc(NB * sizeof(int));
    int*    bucketBase= (int*)alloc((NB + 1) * sizeof(int));
    int*    cursor    = (int*)alloc(NB * sizeof(int));
    int*    rowptr    = (int*)alloc((N_NODES + 1) * sizeof(int));
    int*    col       = (int*)alloc((size_t)N_EDGES * sizeof(int));
    float*  invdeg    = (float*)alloc(N_NODES * sizeof(float));
    ushort* wfrag     = (ushort*)alloc(20480 * sizeof(ushort));
    // shared slot: part (6.4MB) -> xb (12.8MB) -> gb (6.4MB); lifetimes don't overlap
    char*   slot   = (char*)alloc((size_t)N_NODES * 64 * sizeof(ushort));
    int*    part   = (int*)slot;
    ushort* xb     = (ushort*)slot;
    ushort* gb     = (ushort*)slot;
    ushort* meanb  = (ushort*)alloc((size_t)N_NODES * 64 * sizeof(ushort)); // also mean32b
    ushort* mean32b= meanb;
    ushort* hb     = (ushort*)alloc((size_t)N_NODES * 64 * sizeof(ushort));
    float*  out    = (float*)d_out;

    const int TB = 256;
    int castBlocks   = ((N_NODES * 64 / 4) + TB - 1) / TB;
    int g64Blocks    = (N_NODES * 8 + TB - 1) / TB;    // 8 lanes per node
    int g32Blocks    = (N_NODES * 4 + TB - 1) / TB;    // 4 lanes per node
    const int mfmaBlocks = 512;

    // ---- weight-frag prep + CSR build ----
    prep_wfrag<<<80, 256, 0, stream>>>(W1l, W1r, W2l, W2r, W3l, W3r, wfrag);
    hipMemsetAsync(bucketCnt, 0, NB * sizeof(int), stream);
    bucket_hist<<<256, 256, 0, stream>>>(dst, bucketCnt, N_EDGES);
    scan_buckets<<<1, 1024, 0, stream>>>(bucketCnt, bucketBase, cursor);
    partition_kernel<<<256, 256, 0, stream>>>(src, dst, cursor, part, N_EDGES);
    bucket_fill2<<<NB, 256, 0, stream>>>(bucketBase, part, col, rowptr, invdeg, N_NODES);
    cast_bf16<<<castBlocks, TB, 0, stream>>>(x, xb, N_NODES * 64 / 4);  // after bucket_fill2: xb aliases part

    // ---- layer 1 ----
    gather_mean<<<g64Blocks, 256, 0, stream>>>(xb, rowptr, col, invdeg, meanb, N_NODES);
    mfma_transform<<<mfmaBlocks, 256, 0, stream>>>(xb, meanb, wfrag + 0, b1, hb, NTILES);

    // ---- layer 2 ----
    gather_mean<<<g64Blocks, 256, 0, stream>>>(hb, rowptr, col, invdeg, meanb, N_NODES);
    mfma_transform<<<mfmaBlocks, 256, 0, stream>>>(hb, meanb, wfrag + 8192, b2, hb, NTILES);

    // ---- layer 3: pre-transform, 32-wide gather, fused head ----
    mfma_pretrans3<<<mfmaBlocks, 256, 0, stream>>>(hb, wfrag + 16384, gb, NTILES);  // gb aliases xb (dead)
    gather_mean32<<<g32Blocks, 256, 0, stream>>>(gb, rowptr, col, invdeg, mean32b, N_NODES);
    mfma_t3<<<mfmaBlocks, 256, 0, stream>>>(hb, mean32b, wfrag + 18432, b3, Wreg, breg, out, NTILES);
}

// Round 9
// 179.939 us; speedup vs baseline: 12.9254x; 1.0795x over previous
//
#include <hip/hip_runtime.h>
#include <math.h>

#define N_NODES 100000
#define N_EDGES 1600000
#define NB 782              // ceil(N_NODES / 128) buckets, bucket = dst >> 7
#define NTILES 6250         // N_NODES / 16 (exact)

typedef unsigned int uint;
typedef __attribute__((ext_vector_type(8))) short bf16x8;
typedef __attribute__((ext_vector_type(4))) float f32x4;

__device__ inline ushort f2bf(float f) {
    uint u = __float_as_uint(f);
    uint r = (u + 0x7fffu + ((u >> 16) & 1u)) >> 16;
    return (ushort)r;
}
__device__ inline uint pack2bf(float lo, float hi) {
    return (uint)f2bf(lo) | ((uint)f2bf(hi) << 16);
}

// ---------------- cast x -> bf16 ----------------
__global__ void cast_bf16(const float* __restrict__ in, ushort* __restrict__ out, int n4) {
    int i = blockIdx.x * blockDim.x + threadIdx.x;
    if (i < n4) {
        float4 v = ((const float4*)in)[i];
        uint2 o;
        o.x = pack2bf(v.x, v.y);
        o.y = pack2bf(v.z, v.w);
        ((uint2*)out)[i] = o;
    }
}

// ---------------- weight-fragment prep (one-shot, 20480 elems) ----------------
__global__ void prep_wfrag(const float* __restrict__ W1l, const float* __restrict__ W1r,
                           const float* __restrict__ W2l, const float* __restrict__ W2r,
                           const float* __restrict__ W3l, const float* __restrict__ W3r,
                           ushort* __restrict__ wf) {
    int idx = blockIdx.x * 256 + threadIdx.x;
    if (idx >= 20480) return;
    const float *Wl, *Wr;
    int base, KT;
    if (idx < 8192)       { base = 0;     Wl = W1l; Wr = W1r; KT = 128; }
    else if (idx < 16384) { base = 8192;  Wl = W2l; Wr = W2r; KT = 128; }
    else if (idx < 18432) { base = 16384; Wl = W3l; Wr = 0;   KT = 64; }
    else                  { base = 18432; Wl = W3r; Wr = 0;   KT = 64; }
    int r = idx - base;
    int f = r >> 9;
    int l = (r >> 3) & 63;
    int i = r & 7;
    int nks = KT >> 5;
    int nt = f / nks, ks = f - nt * nks;
    int k = ks * 32 + ((l >> 4) << 3) + i;
    int j = nt * 16 + (l & 15);
    float v = (k < 64) ? Wl[j * 64 + k] : Wr[j * 64 + (k - 64)];
    wf[idx] = f2bf(v);
}

// ---------------- bucket-level histogram (LDS pre-aggregation, 1024 thr) ----------------
__global__ void bucket_hist(const int* __restrict__ dst, int* __restrict__ bucketCnt, int nE) {
    __shared__ int hist[NB];
    const int PER = (N_EDGES + 255) / 256;
    int e0 = blockIdx.x * PER;
    int e1 = min(e0 + PER, nE);
    for (int i = threadIdx.x; i < NB; i += 1024) hist[i] = 0;
    __syncthreads();
    for (int e = e0 + threadIdx.x; e < e1; e += 1024)
        atomicAdd(&hist[dst[e] >> 7], 1);
    __syncthreads();
    for (int i = threadIdx.x; i < NB; i += 1024) {
        int c = hist[i];
        if (c) atomicAdd(&bucketCnt[i], c);
    }
}

// ---------------- scan bucket totals -> bucketBase + cursor ----------------
__global__ void scan_buckets(const int* __restrict__ bucketCnt, int* __restrict__ bucketBase,
                             int* __restrict__ cursor) {
    __shared__ int s[1024];
    int tid = threadIdx.x;
    int v = (tid < NB) ? bucketCnt[tid] : 0;
    s[tid] = v;
    __syncthreads();
    for (int off = 1; off < 1024; off <<= 1) {
        int t = (tid >= off) ? s[tid - off] : 0;
        __syncthreads();
        s[tid] += t;
        __syncthreads();
    }
    if (tid < NB) {
        int excl = s[tid] - v;
        bucketBase[tid] = excl;
        cursor[tid] = excl;
    }
    if (tid == 0) bucketBase[NB] = s[NB - 1];
}

// ---------------- partition edges into bucket regions (1024 thr: 16 waves/CU) ----------------
__global__ void partition_kernel(const int* __restrict__ src, const int* __restrict__ dst,
                                 int* __restrict__ cursor, int* __restrict__ part, int nE) {
    __shared__ int hist[NB];
    __shared__ int base[NB];
    __shared__ int rank[NB];
    const int PER = (N_EDGES + 255) / 256;   // 6250 edges per block, 256 blocks
    int e0 = blockIdx.x * PER;
    int e1 = min(e0 + PER, nE);
    for (int i = threadIdx.x; i < NB; i += 1024) { hist[i] = 0; rank[i] = 0; }
    __syncthreads();
    for (int e = e0 + threadIdx.x; e < e1; e += 1024)
        atomicAdd(&hist[dst[e] >> 7], 1);
    __syncthreads();
    for (int i = threadIdx.x; i < NB; i += 1024) {
        int c = hist[i];
        base[i] = c ? atomicAdd(&cursor[i], c) : 0;
    }
    __syncthreads();
    for (int e = e0 + threadIdx.x; e < e1; e += 1024) {
        int d = dst[e];
        int bk = d >> 7;
        int r = atomicAdd(&rank[bk], 1);
        part[base[bk] + r] = src[e] | ((d & 127) << 20);
    }
}

// ---------------- bucket fill: per-dst counts, rowptr, invdeg, col scatter (512 thr) ----------------
__global__ void bucket_fill2(const int* __restrict__ bucketBase, const int* __restrict__ part,
                             int* __restrict__ col, int* __restrict__ rowptr,
                             float* __restrict__ invdeg, int n) {
    __shared__ int cnt[128];
    __shared__ int cnt2[128];
    __shared__ int exclS[128];
    __shared__ int s[128];
    int b = blockIdx.x;
    int d0 = b << 7;
    int dl = min(128, n - d0);
    int ebeg = bucketBase[b], eend = bucketBase[b + 1];
    if (threadIdx.x < 128) { cnt[threadIdx.x] = 0; cnt2[threadIdx.x] = 0; }
    __syncthreads();
    for (int i = ebeg + (int)threadIdx.x; i < eend; i += 512)
        atomicAdd(&cnt[part[i] >> 20], 1);
    __syncthreads();
    if (threadIdx.x < 128) s[threadIdx.x] = cnt[threadIdx.x];
    __syncthreads();
    for (int off = 1; off < 128; off <<= 1) {
        int t = 0;
        if (threadIdx.x < 128 && threadIdx.x >= (unsigned)off) t = s[threadIdx.x - off];
        __syncthreads();
        if (threadIdx.x < 128) s[threadIdx.x] += t;
        __syncthreads();
    }
    if ((int)threadIdx.x < dl) {
        int c = cnt[threadIdx.x];
        int ex = ebeg + s[threadIdx.x] - c;
        rowptr[d0 + threadIdx.x] = ex;
        invdeg[d0 + threadIdx.x] = 1.0f / fmaxf((float)c, 1.0f);
        exclS[threadIdx.x] = ex;
    }
    if (threadIdx.x == 0 && d0 + dl == n) rowptr[n] = eend;
    __syncthreads();
    for (int i = ebeg + (int)threadIdx.x; i < eend; i += 512) {
        int v = part[i];
        int doff = v >> 20;
        int pos = exclS[doff] + atomicAdd(&cnt2[doff], 1);
        col[pos] = v & 0xFFFFF;
    }
}

// ---------------- gather mean (64 bf16 feats): 8-lane group per node, 16B/lane ----------------
__global__ void gather_mean(const ushort* __restrict__ xb, const int* __restrict__ rowptr,
                            const int* __restrict__ col, const float* __restrict__ invdeg,
                            ushort* __restrict__ meanb, int n) {
    int tid = blockIdx.x * blockDim.x + threadIdx.x;
    int wid = tid >> 6;
    int lane = threadIdx.x & 63;
    int grp = lane >> 3;      // 0..7: node within wave
    int li = lane & 7;        // lane in group: feature slice
    int node = wid * 8 + grp;
    if (node >= n) return;
    int beg = rowptr[node];
    int end = rowptr[node + 1];
    int fb = li * 8;
    float a0 = 0.f, a1 = 0.f, a2 = 0.f, a3 = 0.f, a4 = 0.f, a5 = 0.f, a6 = 0.f, a7 = 0.f;
    for (int i = beg; i < end; i += 8) {
        int idx = i + li;
        int ci = (idx < end) ? col[idx] : 0;
        int cnt = end - i;
#pragma unroll
        for (int t = 0; t < 8; ++t) {
            if (t < cnt) {
                int s = __shfl(ci, grp * 8 + t, 64);
                uint4 w = *(const uint4*)(xb + (size_t)s * 64 + fb);
                a0 += __uint_as_float(w.x << 16);
                a1 += __uint_as_float(w.x & 0xffff0000u);
                a2 += __uint_as_float(w.y << 16);
                a3 += __uint_as_float(w.y & 0xffff0000u);
                a4 += __uint_as_float(w.z << 16);
                a5 += __uint_as_float(w.z & 0xffff0000u);
                a6 += __uint_as_float(w.w << 16);
                a7 += __uint_as_float(w.w & 0xffff0000u);
            }
        }
    }
    float id = invdeg[node];
    uint4 o;
    o.x = pack2bf(a0 * id, a1 * id);
    o.y = pack2bf(a2 * id, a3 * id);
    o.z = pack2bf(a4 * id, a5 * id);
    o.w = pack2bf(a6 * id, a7 * id);
    *(uint4*)(meanb + (size_t)node * 64 + fb) = o;
}

// ---------------- gather mean (32 bf16 feats): 4-lane group per node, 16B/lane ----------------
__global__ void gather_mean32(const ushort* __restrict__ gb, const int* __restrict__ rowptr,
                              const int* __restrict__ col, const float* __restrict__ invdeg,
                              ushort* __restrict__ mean32b, int n) {
    int tid = blockIdx.x * blockDim.x + threadIdx.x;
    int wid = tid >> 6;
    int lane = threadIdx.x & 63;
    int grp = lane >> 2;      // 0..15: node within wave
    int li = lane & 3;        // feature slice
    int node = wid * 16 + grp;
    if (node >= n) return;
    int beg = rowptr[node];
    int end = rowptr[node + 1];
    int fb = li * 8;
    float a0 = 0.f, a1 = 0.f, a2 = 0.f, a3 = 0.f, a4 = 0.f, a5 = 0.f, a6 = 0.f, a7 = 0.f;
    for (int i = beg; i < end; i += 4) {
        int idx = i + li;
        int ci = (idx < end) ? col[idx] : 0;
        int cnt = end - i;
#pragma unroll
        for (int t = 0; t < 4; ++t) {
            if (t < cnt) {
                int s = __shfl(ci, grp * 4 + t, 64);
                uint4 w = *(const uint4*)(gb + (size_t)s * 32 + fb);
                a0 += __uint_as_float(w.x << 16);
                a1 += __uint_as_float(w.x & 0xffff0000u);
                a2 += __uint_as_float(w.y << 16);
                a3 += __uint_as_float(w.y & 0xffff0000u);
                a4 += __uint_as_float(w.z << 16);
                a5 += __uint_as_float(w.z & 0xffff0000u);
                a6 += __uint_as_float(w.w << 16);
                a7 += __uint_as_float(w.w & 0xffff0000u);
            }
        }
    }
    float id = invdeg[node];
    uint4 o;
    o.x = pack2bf(a0 * id, a1 * id);
    o.y = pack2bf(a2 * id, a3 * id);
    o.z = pack2bf(a4 * id, a5 * id);
    o.w = pack2bf(a6 * id, a7 * id);
    *(uint4*)(mean32b + (size_t)node * 32 + fb) = o;
}

// ---------------- MFMA transform (layers 1,2): h = relu([mean|x] @ Wcomb + b) ----------------
__global__ void __launch_bounds__(256)
mfma_transform(const ushort* __restrict__ rootb, const ushort* __restrict__ meanb,
               const ushort* __restrict__ wfrag, const float* __restrict__ bias,
               ushort* __restrict__ outb, int ntiles) {
    int wave = threadIdx.x >> 6;
    int lane = threadIdx.x & 63;

    bf16x8 wf[4][4];
#pragma unroll
    for (int nt = 0; nt < 4; ++nt)
#pragma unroll
        for (int ks = 0; ks < 4; ++ks)
            wf[nt][ks] = *(const bf16x8*)(wfrag + (size_t)((nt * 4 + ks) * 64 + lane) * 8);

    float bl[4];
#pragma unroll
    for (int nt = 0; nt < 4; ++nt) bl[nt] = bias[nt * 16 + (lane & 15)];

    int arow = lane & 15;
    int koff = (lane >> 4) * 8;
    int crow = (lane >> 4) * 4;
    int nwaves = gridDim.x * 4;

    for (int tile = blockIdx.x * 4 + wave; tile < ntiles; tile += nwaves) {
        int n0 = tile * 16;
        const ushort* mrow = meanb + (size_t)(n0 + arow) * 64 + koff;
        const ushort* xrow = rootb + (size_t)(n0 + arow) * 64 + koff;
        bf16x8 a0 = *(const bf16x8*)(mrow);
        bf16x8 a1 = *(const bf16x8*)(mrow + 32);
        bf16x8 a2 = *(const bf16x8*)(xrow);
        bf16x8 a3 = *(const bf16x8*)(xrow + 32);
#pragma unroll
        for (int nt = 0; nt < 4; ++nt) {
            f32x4 c = {0.f, 0.f, 0.f, 0.f};
            c = __builtin_amdgcn_mfma_f32_16x16x32_bf16(a0, wf[nt][0], c, 0, 0, 0);
            c = __builtin_amdgcn_mfma_f32_16x16x32_bf16(a1, wf[nt][1], c, 0, 0, 0);
            c = __builtin_amdgcn_mfma_f32_16x16x32_bf16(a2, wf[nt][2], c, 0, 0, 0);
            c = __builtin_amdgcn_mfma_f32_16x16x32_bf16(a3, wf[nt][3], c, 0, 0, 0);
#pragma unroll
            for (int i = 0; i < 4; ++i) {
                float v = fmaxf(c[i] + bl[nt], 0.0f);
                outb[(size_t)(n0 + crow + i) * 64 + nt * 16 + (lane & 15)] = f2bf(v);
            }
        }
    }
}

// ---------------- MFMA pre-transform layer 3: g = h @ W3l.T (K=64, N=32) ----------------
__global__ void __launch_bounds__(256)
mfma_pretrans3(const ushort* __restrict__ hb, const ushort* __restrict__ wfrag,
               ushort* __restrict__ gb, int ntiles) {
    int wave = threadIdx.x >> 6;
    int lane = threadIdx.x & 63;

    bf16x8 wf[2][2];
#pragma unroll
    for (int nt = 0; nt < 2; ++nt)
#pragma unroll
        for (int ks = 0; ks < 2; ++ks)
            wf[nt][ks] = *(const bf16x8*)(wfrag + (size_t)((nt * 2 + ks) * 64 + lane) * 8);

    int arow = lane & 15;
    int koff = (lane >> 4) * 8;
    int crow = (lane >> 4) * 4;
    int nwaves = gridDim.x * 4;

    for (int tile = blockIdx.x * 4 + wave; tile < ntiles; tile += nwaves) {
        int n0 = tile * 16;
        const ushort* hrow = hb + (size_t)(n0 + arow) * 64 + koff;
        bf16x8 a0 = *(const bf16x8*)(hrow);
        bf16x8 a1 = *(const bf16x8*)(hrow + 32);
#pragma unroll
        for (int nt = 0; nt < 2; ++nt) {
            f32x4 c = {0.f, 0.f, 0.f, 0.f};
            c = __builtin_amdgcn_mfma_f32_16x16x32_bf16(a0, wf[nt][0], c, 0, 0, 0);
            c = __builtin_amdgcn_mfma_f32_16x16x32_bf16(a1, wf[nt][1], c, 0, 0, 0);
#pragma unroll
            for (int i = 0; i < 4; ++i)
                gb[(size_t)(n0 + crow + i) * 32 + nt * 16 + (lane & 15)] = f2bf(c[i]);
        }
    }
}

// ---------------- MFMA layer 3 + head ----------------
__global__ void __launch_bounds__(256)
mfma_t3(const ushort* __restrict__ hb, const ushort* __restrict__ mean32b,
        const ushort* __restrict__ wfrag, const float* __restrict__ b3,
        const float* __restrict__ Wreg, const float* __restrict__ breg,
        float* __restrict__ out, int ntiles) {
    int wave = threadIdx.x >> 6;
    int lane = threadIdx.x & 63;

    bf16x8 wf[2][2];
#pragma unroll
    for (int nt = 0; nt < 2; ++nt)
#pragma unroll
        for (int ks = 0; ks < 2; ++ks)
            wf[nt][ks] = *(const bf16x8*)(wfrag + (size_t)((nt * 2 + ks) * 64 + lane) * 8);

    float bl[2], wr[2];
#pragma unroll
    for (int nt = 0; nt < 2; ++nt) {
        bl[nt] = b3[nt * 16 + (lane & 15)];
        wr[nt] = Wreg[nt * 16 + (lane & 15)];
    }
    float br = breg[0];

    int arow = lane & 15;
    int koff = (lane >> 4) * 8;
    int crow = (lane >> 4) * 4;
    int nwaves = gridDim.x * 4;

    for (int tile = blockIdx.x * 4 + wave; tile < ntiles; tile += nwaves) {
        int n0 = tile * 16;
        const ushort* hrow = hb + (size_t)(n0 + arow) * 64 + koff;
        bf16x8 a0 = *(const bf16x8*)(hrow);
        bf16x8 a1 = *(const bf16x8*)(hrow + 32);
        float part0 = 0.f, part1 = 0.f, part2 = 0.f, part3 = 0.f;
#pragma unroll
        for (int nt = 0; nt < 2; ++nt) {
            f32x4 c = {0.f, 0.f, 0.f, 0.f};
            c = __builtin_amdgcn_mfma_f32_16x16x32_bf16(a0, wf[nt][0], c, 0, 0, 0);
            c = __builtin_amdgcn_mfma_f32_16x16x32_bf16(a1, wf[nt][1], c, 0, 0, 0);
#pragma unroll
            for (int i = 0; i < 4; ++i) {
                ushort mw = mean32b[(size_t)(n0 + crow + i) * 32 + nt * 16 + (lane & 15)];
                float m = __uint_as_float((uint)mw << 16);
                float v = fmaxf(c[i] + bl[nt] + m, 0.0f) * wr[nt];
                if (i == 0) part0 += v;
                else if (i == 1) part1 += v;
                else if (i == 2) part2 += v;
                else part3 += v;
            }
        }
#pragma unroll
        for (int s = 1; s < 16; s <<= 1) {
            part0 += __shfl_xor(part0, s, 64);
            part1 += __shfl_xor(part1, s, 64);
            part2 += __shfl_xor(part2, s, 64);
            part3 += __shfl_xor(part3, s, 64);
        }
        if ((lane & 15) == 0) {
            float4 o;
            o.x = part0 + br; o.y = part1 + br; o.z = part2 + br; o.w = part3 + br;
            *(float4*)(out + n0 + crow) = o;
        }
    }
}

extern "C" void kernel_launch(void* const* d_in, const int* in_sizes, int n_in,
                              void* d_out, int out_size, void* d_ws, size_t ws_size,
                              hipStream_t stream) {
    const float* x    = (const float*)d_in[0];
    const int*   ei   = (const int*)d_in[1];
    const float* W1l  = (const float*)d_in[2];
    const float* b1   = (const float*)d_in[3];
    const float* W1r  = (const float*)d_in[4];
    const float* W2l  = (const float*)d_in[5];
    const float* b2   = (const float*)d_in[6];
    const float* W2r  = (const float*)d_in[7];
    const float* W3l  = (const float*)d_in[8];
    const float* b3   = (const float*)d_in[9];
    const float* W3r  = (const float*)d_in[10];
    const float* Wreg = (const float*)d_in[11];
    const float* breg = (const float*)d_in[12];

    const int* src = ei;
    const int* dst = ei + N_EDGES;

    char* p = (char*)d_ws;
    auto alloc = [&](size_t bytes) {
        char* r = p;
        p += (bytes + 255) & ~(size_t)255;
        return r;
    };
    int*    bucketCnt = (int*)alloc(NB * sizeof(int));
    int*    bucketBase= (int*)alloc((NB + 1) * sizeof(int));
    int*    cursor    = (int*)alloc(NB * sizeof(int));
    int*    rowptr    = (int*)alloc((N_NODES + 1) * sizeof(int));
    int*    col       = (int*)alloc((size_t)N_EDGES * sizeof(int));
    float*  invdeg    = (float*)alloc(N_NODES * sizeof(float));
    ushort* wfrag     = (ushort*)alloc(20480 * sizeof(ushort));
    // shared slot: part (6.4MB) -> xb (12.8MB) -> gb (6.4MB); lifetimes don't overlap
    char*   slot   = (char*)alloc((size_t)N_NODES * 64 * sizeof(ushort));
    int*    part   = (int*)slot;
    ushort* xb     = (ushort*)slot;
    ushort* gb     = (ushort*)slot;
    ushort* meanb  = (ushort*)alloc((size_t)N_NODES * 64 * sizeof(ushort)); // also mean32b
    ushort* mean32b= meanb;
    ushort* hb     = (ushort*)alloc((size_t)N_NODES * 64 * sizeof(ushort));
    float*  out    = (float*)d_out;

    const int TB = 256;
    int castBlocks   = ((N_NODES * 64 / 4) + TB - 1) / TB;
    int g64Blocks    = (N_NODES * 8 + TB - 1) / TB;    // 8 lanes per node
    int g32Blocks    = (N_NODES * 4 + TB - 1) / TB;    // 4 lanes per node
    const int mfmaBlocks = 512;

    // ---- weight-frag prep + CSR build ----
    prep_wfrag<<<80, 256, 0, stream>>>(W1l, W1r, W2l, W2r, W3l, W3r, wfrag);
    hipMemsetAsync(bucketCnt, 0, NB * sizeof(int), stream);
    bucket_hist<<<256, 1024, 0, stream>>>(dst, bucketCnt, N_EDGES);
    scan_buckets<<<1, 1024, 0, stream>>>(bucketCnt, bucketBase, cursor);
    partition_kernel<<<256, 1024, 0, stream>>>(src, dst, cursor, part, N_EDGES);
    bucket_fill2<<<NB, 512, 0, stream>>>(bucketBase, part, col, rowptr, invdeg, N_NODES);
    cast_bf16<<<castBlocks, TB, 0, stream>>>(x, xb, N_NODES * 64 / 4);  // after bucket_fill2: xb aliases part

    // ---- layer 1 ----
    gather_mean<<<g64Blocks, 256, 0, stream>>>(xb, rowptr, col, invdeg, meanb, N_NODES);
    mfma_transform<<<mfmaBlocks, 256, 0, stream>>>(xb, meanb, wfrag + 0, b1, hb, NTILES);

    // ---- layer 2 ----
    gather_mean<<<g64Blocks, 256, 0, stream>>>(hb, rowptr, col, invdeg, meanb, N_NODES);
    mfma_transform<<<mfmaBlocks, 256, 0, stream>>>(hb, meanb, wfrag + 8192, b2, hb, NTILES);

    // ---- layer 3: pre-transform, 32-wide gather, fused head ----
    mfma_pretrans3<<<mfmaBlocks, 256, 0, stream>>>(hb, wfrag + 16384, gb, NTILES);  // gb aliases xb (dead)
    gather_mean32<<<g32Blocks, 256, 0, stream>>>(gb, rowptr, col, invdeg, mean32b, N_NODES);
    mfma_t3<<<mfmaBlocks, 256, 0, stream>>>(hb, mean32b, wfrag + 18432, b3, Wreg, breg, out, NTILES);
}